// Round 15
// baseline (533.412 us; speedup 1.0000x reference)
//
#include <hip/hip_runtime.h>
#include <cmath>

#define DMODEL 768
#define SEQ    1024
#define NH     12
#define HDIM   64
#define MTOT   16384   // 16 * 1024

typedef unsigned short ushort_t;
typedef __attribute__((ext_vector_type(8))) short short8v;
typedef __attribute__((ext_vector_type(4))) float f32x4;
typedef __attribute__((ext_vector_type(16))) float f32x16;
typedef __attribute__((ext_vector_type(2))) int i32x2v;

union v8u { short8v v; unsigned u[4]; };

// round-to-nearest-even fp32 -> bf16 bits (scalar, small kernels)
__device__ __forceinline__ ushort_t bf16rn(float x) {
  unsigned u = __float_as_uint(x);
  return (ushort_t)((u + 0x7FFFu + ((u >> 16) & 1u)) >> 16);
}
__device__ __forceinline__ void bsplit(float x, ushort_t& h, ushort_t& l) {
  h = bf16rn(x);
  float hf = __uint_as_float((unsigned)h << 16);
  l = bf16rn(x - hf);
}

// packed 2xf32 -> 2xbf16 (RNE): lo16 = bf16(a), hi16 = bf16(b)
__device__ __forceinline__ unsigned cvt_pk_bf16(float a, float b) {
  unsigned r;
  asm("v_cvt_pk_bf16_f32 %0, %1, %2" : "=v"(r) : "v"(a), "v"(b));
  return r;
}
// split two f32 into packed-bf16 hi-word and lo-word (element0 in lo16)
__device__ __forceinline__ void bsplit2(float x0, float x1, unsigned& hw, unsigned& lw) {
  hw = cvt_pk_bf16(x0, x1);
  const float h0 = __uint_as_float(hw << 16);
  const float h1 = __uint_as_float(hw & 0xFFFF0000u);
  lw = cvt_pk_bf16(x0 - h0, x1 - h1);
}

// single-instruction 3-input max (exact)
__device__ __forceinline__ float vmax3(float a, float b, float c) {
  float d;
  asm("v_max3_f32 %0, %1, %2, %3" : "=v"(d) : "v"(a), "v"(b), "v"(c));
  return d;
}

// v_permlane32_swap_b32: ret[0] = own a (lanes<32) | partner b (lanes>=32)
//                        ret[1] = partner a (lanes<32) | own b (lanes>=32)
__device__ __forceinline__ i32x2v pl32(unsigned a, unsigned b) {
  return __builtin_amdgcn_permlane32_swap((int)a, (int)b, false, false);
}

// async global -> LDS, 16 bytes per lane
__device__ __forceinline__ void gld16(const void* g, void* l) {
  __builtin_amdgcn_global_load_lds(
      (const __attribute__((address_space(1))) int*)g,
      (__attribute__((address_space(3))) int*)l, 16, 0, 0);
}

// ---------------------------------------------------------------------------
// Weight transpose+split body: W [768k][768n] fp32 -> hi/lo bf16 [768n][768k]
// ---------------------------------------------------------------------------
__device__ __forceinline__
void wsplit_body(const float* __restrict__ W, ushort_t* __restrict__ TH,
                 ushort_t* __restrict__ TL, int kt, int nt, int t, float* Tls) {
  float (*T)[65] = (float(*)[65])Tls;
  const int r = t >> 2, c4 = (t & 3) * 16;
  const float* src = W + (size_t)(kt * 64 + r) * DMODEL + nt * 64 + c4;
#pragma unroll
  for (int i = 0; i < 16; i += 4)
    *(float4*)&T[r][c4 + i] = *(const float4*)&src[i];
  __syncthreads();
  short8v h0, h1, l0, l1;
#pragma unroll
  for (int i = 0; i < 8; ++i) {
    ushort_t hh, ll;
    bsplit(T[c4 + i][r], hh, ll);
    h0[i] = (short)hh; l0[i] = (short)ll;
  }
#pragma unroll
  for (int i = 0; i < 8; ++i) {
    ushort_t hh, ll;
    bsplit(T[c4 + 8 + i][r], hh, ll);
    h1[i] = (short)hh; l1[i] = (short)ll;
  }
  const size_t o = (size_t)(nt * 64 + r) * DMODEL + kt * 64 + c4;
  *(short8v*)&TH[o] = h0; *(short8v*)&TH[o + 8] = h1;
  *(short8v*)&TL[o] = l0; *(short8v*)&TL[o + 8] = l1;
}

// ---------------------------------------------------------------------------
// Prep kernel: blocks 0..63 = RoPE tables; 64.. = Wq/Wk/Wv transpose+split
// ---------------------------------------------------------------------------
__global__ __launch_bounds__(256)
void prep_kernel(float* __restrict__ tab,
                 const float* __restrict__ Wq, ushort_t* __restrict__ QH, ushort_t* __restrict__ QL,
                 const float* __restrict__ Wk, ushort_t* __restrict__ KH, ushort_t* __restrict__ KL,
                 const float* __restrict__ Wv, ushort_t* __restrict__ VH, ushort_t* __restrict__ VL) {
  __shared__ __align__(16) float Tls[64 * 65];
  const int bx = blockIdx.x, t = threadIdx.x;
  if (bx < 64) {
    int idx = bx * 256 + t;
    int l = idx >> 4, p = idx & 15;
    double u = ((double)(l & 31) + 0.5) / 32.0;
    double v = ((double)(l >> 5) + 0.5) / 32.0;
    double freq = (double)p / (15.0 + 1e-9);
    double inv = pow(10000.0, -freq);
    tab[idx]         = (float)cos(u * inv);
    tab[16384 + idx] = (float)sin(u * inv);
    tab[32768 + idx] = (float)cos(v * inv);
    tab[49152 + idx] = (float)sin(v * inv);
    return;
  }
  const int wi = (bx - 64) / 144, b = (bx - 64) % 144;
  const int kt = b % 12, nt = b / 12;
  if (wi == 0)      wsplit_body(Wq, QH, QL, kt, nt, t, Tls);
  else if (wi == 1) wsplit_body(Wk, KH, KL, kt, nt, t, Tls);
  else              wsplit_body(Wv, VH, VL, kt, nt, t, Tls);
}

// standalone wsplit for Wo (must run after attn: output aliases q-buffers)
__global__ __launch_bounds__(256)
void wsplit_t_kernel(const float* __restrict__ W, ushort_t* __restrict__ TH,
                     ushort_t* __restrict__ TL) {
  __shared__ __align__(16) float Tls[64 * 65];
  wsplit_body(W, TH, TL, blockIdx.x, blockIdx.y, threadIdx.x, Tls);
}

// ---------------------------------------------------------------------------
// Split-bf16 MFMA GEMM: C[16384,768] = A @ B + bias (3-term hi/lo).
// AFP32=1: A fp32, staged swizzled + split in-register (bit-identical).
// VT=1: mode-2 epilogue writes V^T [n][h][d][1024] hi/lo directly via
//       in-block LDS transpose (reuses Araw/Bh/Bl after the K-loop).
// Grid: x = N-tile (6), y = M-tile (128).
// ---------------------------------------------------------------------------
template<int AFP32, int VT>
__global__ __launch_bounds__(256)
void gemm_mfma_kernel(const float* __restrict__ Af,
                      const ushort_t* __restrict__ Ahi, const ushort_t* __restrict__ Alo,
                      const ushort_t* __restrict__ Bhi, const ushort_t* __restrict__ Blo,
                      const float* __restrict__ bias, float* __restrict__ Cout,
                      ushort_t* __restrict__ Ohi, ushort_t* __restrict__ Olo,
                      const float* __restrict__ rope, int mode, float oscale) {
  __shared__ __align__(16) unsigned char Araw[16384];   // 16 KB: hi+lo OR fp32
  __shared__ __align__(16) ushort_t Bh[128][32];
  __shared__ __align__(16) ushort_t Bl[128][32];
  ushort_t (*Ah)[32] = (ushort_t(*)[32])Araw;
  ushort_t (*Al)[32] = (ushort_t(*)[32])(Araw + 8192);
  float* Afs = (float*)Araw;                            // [128][32] floats

  const int t = threadIdx.x, lane = t & 63, w = t >> 6;
  const int l15 = lane & 15, l4 = lane >> 4;
  const int wm = w >> 1, wn = w & 1;
  const int m0 = blockIdx.y * 128, n0 = blockIdx.x * 128;

  const int crow = t >> 2, ccc = (t & 3) * 8;
  const ushort_t* pBh0 = Bhi + (size_t)(n0 + crow) * DMODEL + ccc;
  const ushort_t* pBh1 = pBh0 + (size_t)64 * DMODEL;
  const ushort_t* pBl0 = Blo + (size_t)(n0 + crow) * DMODEL + ccc;
  const ushort_t* pBl1 = pBl0 + (size_t)64 * DMODEL;
  void* dBh0 = &Bh[crow][ccc];      void* dBh1 = &Bh[crow + 64][ccc];
  void* dBl0 = &Bl[crow][ccc];      void* dBl1 = &Bl[crow + 64][ccc];

  const int sr8 = lane >> 3, sc8 = lane & 7, sg = sc8 ^ sr8;
  const ushort_t* pAh0 = nullptr; const ushort_t* pAh1 = nullptr;
  const ushort_t* pAl0 = nullptr; const ushort_t* pAl1 = nullptr;
  void* dAh0 = nullptr; void* dAh1 = nullptr; void* dAl0 = nullptr; void* dAl1 = nullptr;
  if (!AFP32) {
    pAh0 = Ahi + (size_t)(m0 + crow) * DMODEL + ccc;
    pAh1 = pAh0 + (size_t)64 * DMODEL;
    pAl0 = Alo + (size_t)(m0 + crow) * DMODEL + ccc;
    pAl1 = pAl0 + (size_t)64 * DMODEL;
    dAh0 = &Ah[crow][ccc];  dAh1 = &Ah[crow + 64][ccc];
    dAl0 = &Al[crow][ccc];  dAl1 = &Al[crow + 64][ccc];
  }

  f32x4 acc[4][4] = {};

  for (int ks = 0; ks < DMODEL / 32; ++ks) {
    __syncthreads();
    if (AFP32) {
#pragma unroll
      for (int j = 0; j < 4; ++j) {
        const int row = j * 32 + w * 8 + sr8;
        gld16(Af + (size_t)(m0 + row) * DMODEL + ks * 32 + sg * 4,
              &Afs[row * 32 + sc8 * 4]);
      }
    } else {
      gld16(pAh0, dAh0); gld16(pAh1, dAh1);
      gld16(pAl0, dAl0); gld16(pAl1, dAl1);
      pAh0 += 32; pAh1 += 32; pAl0 += 32; pAl1 += 32;
    }
    gld16(pBh0, dBh0); gld16(pBh1, dBh1);
    gld16(pBl0, dBl0); gld16(pBl1, dBl1);
    pBh0 += 32; pBh1 += 32; pBl0 += 32; pBl1 += 32;
    __syncthreads();

    short8v afh[4], afl[4], bfh[4], bfl[4];
#pragma unroll
    for (int f = 0; f < 4; ++f) {
      if (AFP32) {
        const int row = wm * 64 + f * 16 + l15;
        const int rs = l15 & 7;
        const float* ap = Afs + row * 32;
        const f32x4 x0 = *(const f32x4*)(ap + (((2 * l4)     ^ rs) * 4));
        const f32x4 x1 = *(const f32x4*)(ap + (((2 * l4 + 1) ^ rs) * 4));
        v8u hh, ll;
        bsplit2(x0[0], x0[1], hh.u[0], ll.u[0]);
        bsplit2(x0[2], x0[3], hh.u[1], ll.u[1]);
        bsplit2(x1[0], x1[1], hh.u[2], ll.u[2]);
        bsplit2(x1[2], x1[3], hh.u[3], ll.u[3]);
        afh[f] = hh.v; afl[f] = ll.v;
      } else {
        afh[f] = *(const short8v*)&Ah[wm * 64 + f * 16 + l15][l4 * 8];
        afl[f] = *(const short8v*)&Al[wm * 64 + f * 16 + l15][l4 * 8];
      }
      bfh[f] = *(const short8v*)&Bh[wn * 64 + f * 16 + l15][l4 * 8];
      bfl[f] = *(const short8v*)&Bl[wn * 64 + f * 16 + l15][l4 * 8];
    }
#pragma unroll
    for (int mf = 0; mf < 4; ++mf)
#pragma unroll
      for (int nf = 0; nf < 4; ++nf) {
        acc[mf][nf] = __builtin_amdgcn_mfma_f32_16x16x32_bf16(afh[mf], bfh[nf], acc[mf][nf], 0, 0, 0);
        acc[mf][nf] = __builtin_amdgcn_mfma_f32_16x16x32_bf16(afl[mf], bfh[nf], acc[mf][nf], 0, 0, 0);
        acc[mf][nf] = __builtin_amdgcn_mfma_f32_16x16x32_bf16(afh[mf], bfl[nf], acc[mf][nf], 0, 0, 0);
      }
  }

  float bcol[4];
#pragma unroll
  for (int nf = 0; nf < 4; ++nf) bcol[nf] = bias[n0 + wn * 64 + nf * 16 + l15];

  if (VT) {
    // ---- fused V^T epilogue: transpose 128x128 tile through LDS, store
    // [n][h][d][1024] hi/lo. Same bsplit2 values as mode 2 -> bit-identical.
    ushort_t* hiT = (ushort_t*)Araw;          // [64 d][128 l], chunk-XOR layout
    ushort_t* loTa = (ushort_t*)Bh;           // d <  32
    ushort_t* loTb = (ushort_t*)Bl;           // d >= 32
    const int nb = blockIdx.y >> 3;
    const int l0 = (blockIdx.y & 7) * 128;
#pragma unroll
    for (int hs = 0; hs < 2; ++hs) {
      __syncthreads();
      if (wn == hs) {
#pragma unroll
        for (int mf = 0; mf < 4; ++mf)
#pragma unroll
          for (int r = 0; r < 4; ++r) {
            const int ll = wm * 64 + mf * 16 + l4 * 4 + r;
            const int lg = ll >> 3, li = ll & 7;
            unsigned h01, lo01, h23, lo23;
            bsplit2(acc[mf][0][r] + bcol[0], acc[mf][1][r] + bcol[1], h01, lo01);
            bsplit2(acc[mf][2][r] + bcol[2], acc[mf][3][r] + bcol[3], h23, lo23);
            const ushort_t hv[4] = {(ushort_t)(h01 & 0xFFFFu), (ushort_t)(h01 >> 16),
                                    (ushort_t)(h23 & 0xFFFFu), (ushort_t)(h23 >> 16)};
            const ushort_t lv[4] = {(ushort_t)(lo01 & 0xFFFFu), (ushort_t)(lo01 >> 16),
                                    (ushort_t)(lo23 & 0xFFFFu), (ushort_t)(lo23 >> 16)};
#pragma unroll
            for (int nf = 0; nf < 4; ++nf) {
              const int d = nf * 16 + l15;
              const int off = ((lg ^ (d & 7)) << 3) + li;
              hiT[d * 128 + off] = hv[nf];
              if (nf < 2) loTa[d * 128 + off] = lv[nf];
              else        loTb[(d - 32) * 128 + off] = lv[nf];
            }
          }
      }
      __syncthreads();
      {
        const int d = t >> 2;
        const int hglob = blockIdx.x * 2 + hs;
        const size_t dst = ((size_t)(nb * NH + hglob) * HDIM + d) * SEQ + l0;
#pragma unroll
        for (int j = 0; j < 4; ++j) {
          const int lg = (t & 3) * 4 + j;
          const int off = (lg ^ (d & 7)) << 3;
          const short8v hv = *(const short8v*)&hiT[d * 128 + off];
          const short8v lv = (d < 32) ? *(const short8v*)&loTa[d * 128 + off]
                                      : *(const short8v*)&loTb[(d - 32) * 128 + off];
          *(short8v*)&Ohi[dst + lg * 8] = hv;
          *(short8v*)&Olo[dst + lg * 8] = lv;
        }
      }
    }
  } else if (mode == 0) {
#pragma unroll
    for (int mf = 0; mf < 4; ++mf)
#pragma unroll
      for (int r = 0; r < 4; ++r) {
        const int m = m0 + wm * 64 + mf * 16 + l4 * 4 + r;
#pragma unroll
        for (int nf = 0; nf < 4; ++nf)
          Cout[(size_t)m * DMODEL + n0 + wn * 64 + nf * 16 + l15] = acc[mf][nf][r] + bcol[nf];
      }
  } else {
    const int h = blockIdx.x * 2 + wn;
#pragma unroll
    for (int mf = 0; mf < 4; ++mf)
#pragma unroll
      for (int r = 0; r < 4; ++r) {
        const int m = m0 + wm * 64 + mf * 16 + l4 * 4 + r;
        const int l = m & (SEQ - 1);
        const int nb = m >> 10;
        const size_t orow = ((size_t)(nb * NH + h) * SEQ + l) * HDIM;
        float vv[4];
#pragma unroll
        for (int nf = 0; nf < 4; ++nf) {
          float v = acc[mf][nf][r] + bcol[nf];
          if (mode == 1) {
            const float vp = __shfl_xor(v, 1, 64);
            const int tb = (nf < 2) ? 0 : 32768;
            const int pi = (nf & 1) * 8 + (l15 >> 1);
            const float c = rope[tb + l * 16 + pi];
            const float s = rope[tb + 16384 + l * 16 + pi];
            v = (l15 & 1) ? (vp * s + v * c) : (v * c - vp * s);
            v *= oscale;   // Q: log2e/8 (exp2-domain); K: 1.0
          }
          vv[nf] = v;
        }
        unsigned h01, l01, h23, l23;
        bsplit2(vv[0], vv[1], h01, l01);
        bsplit2(vv[2], vv[3], h23, l23);
        Ohi[orow + 0 * 16 + l15] = (ushort_t)(h01 & 0xFFFFu);
        Ohi[orow + 1 * 16 + l15] = (ushort_t)(h01 >> 16);
        Ohi[orow + 2 * 16 + l15] = (ushort_t)(h23 & 0xFFFFu);
        Ohi[orow + 3 * 16 + l15] = (ushort_t)(h23 >> 16);
        Olo[orow + 0 * 16 + l15] = (ushort_t)(l01 & 0xFFFFu);
        Olo[orow + 1 * 16 + l15] = (ushort_t)(l01 >> 16);
        Olo[orow + 2 * 16 + l15] = (ushort_t)(l23 & 0xFFFFu);
        Olo[orow + 3 * 16 + l15] = (ushort_t)(l23 >> 16);
      }
  }
}

// ---------------------------------------------------------------------------
// Flash attention: QBLK=256 (8 waves / 512 thr, 4 waves/SIMD for cross-wave
// MFMA/VALU overlap), 32x32x16 MFMA, swapped QK^T, permlane32_swap
// P-redistribution, K+V double-buffered via global_load_lds + pre-swizzled
// source, 1 barrier/kt, 64 KB LDS. Per-wave structure identical to R13.
// ---------------------------------------------------------------------------
__global__ __launch_bounds__(512)
void attn_mfma_kernel(const ushort_t* __restrict__ qh, const ushort_t* __restrict__ ql,
                      const ushort_t* __restrict__ kh, const ushort_t* __restrict__ kl,
                      const ushort_t* __restrict__ vth, const ushort_t* __restrict__ vtl,
                      ushort_t* __restrict__ abh, ushort_t* __restrict__ abl) {
  __shared__ __align__(16) ushort_t KHs[2][64][64];
  __shared__ __align__(16) ushort_t KLs[2][64][64];
  __shared__ __align__(16) ushort_t VHs[2][64][64];
  __shared__ __align__(16) ushort_t VLs[2][64][64];

  const int t = threadIdx.x;
  const int lane = t & 63, w = t >> 6;       // 8 waves
  const int l31 = lane & 31, l1 = lane >> 5;

  const int bid = blockIdx.x;                // 768 blocks
  const int xcd = bid & 7, rest = bid >> 3;
  const int qt = rest & 3;                   // 4 q-tiles of 256 rows
  const int hl = (rest >> 2) * 8 + xcd;      // head pinned to XCD
  const int h = hl % NH, n = hl / NH;

  const size_t base = (size_t)(n * NH + h) * (SEQ * HDIM);

  short8v qfh[4], qfl[4];
  {
    const size_t qoff = base + (size_t)(qt * 256 + w * 32 + l31) * HDIM + l1 * 8;
#pragma unroll
    for (int ks = 0; ks < 4; ++ks) {
      qfh[ks] = *(const short8v*)&qh[qoff + ks * 16];
      qfl[ks] = *(const short8v*)&ql[qoff + ks * 16];
    }
  }

  // staging: wave w stages 8-row segment w of each of KH/KL/VH/VL (4 gld16).
  // swizzle law preserved: (w*8+srow)&7 == srow.
  const int srow = lane >> 3;
  const int schk = (lane & 7) ^ srow;
  const size_t kof = base + (size_t)(w * 8 + srow) * HDIM + schk * 8;
  const size_t vof = base + (size_t)(w * 8 + srow) * SEQ + schk * 8;
  const int dr = w * 8 + srow, dc = (lane & 7) * 8;

  f32x16 Oa0 = {}, Oa1 = {};
  f32x16 lpv = {};
  float mrun = 0.0f;

#define ATTN_ISSUE(kt_, b_) do {                                            \
    const size_t ko_ = (size_t)(kt_) * (64 * HDIM);                         \
    const size_t vo_ = (size_t)(kt_) * 64;                                  \
    gld16(kh  + kof + ko_, &KHs[b_][dr][dc]);                               \
    gld16(kl  + kof + ko_, &KLs[b_][dr][dc]);                               \
    gld16(vth + vof + vo_, &VHs[b_][dr][dc]);                               \
    gld16(vtl + vof + vo_, &VLs[b_][dr][dc]);                               \
  } while (0)

  ATTN_ISSUE(0, 0);

  for (int kt = 0; kt < 16; ++kt) {
    const int cur = kt & 1;
    __syncthreads();
    if (kt < 15) ATTN_ISSUE(kt + 1, cur ^ 1);

    f32x16 S0 = {}, S1 = {};
    __builtin_amdgcn_s_setprio(1);
#pragma unroll
    for (int ks = 0; ks < 4; ++ks) {
      const int cc = ((2 * ks + l1) ^ (l31 & 7)) * 8;
      const short8v k0h = *(const short8v*)&KHs[cur][l31][cc];
      const short8v k0l = *(const short8v*)&KLs[cur][l31][cc];
      const short8v k1h = *(const short8v*)&KHs[cur][32 + l31][cc];
      const short8v k1l = *(const short8v*)&KLs[cur][32 + l31][cc];
      S0 = __builtin_amdgcn_mfma_f32_32x32x16_bf16(k0h, qfh[ks], S0, 0, 0, 0);
      S1 = __builtin_amdgcn_mfma_f32_32x32x16_bf16(k1h, qfh[ks], S1, 0, 0, 0);
      S0 = __builtin_amdgcn_mfma_f32_32x32x16_bf16(k0l, qfh[ks], S0, 0, 0, 0);
      S1 = __builtin_amdgcn_mfma_f32_32x32x16_bf16(k1l, qfh[ks], S1, 0, 0, 0);
      S0 = __builtin_amdgcn_mfma_f32_32x32x16_bf16(k0h, qfl[ks], S0, 0, 0, 0);
      S1 = __builtin_amdgcn_mfma_f32_32x32x16_bf16(k1h, qfl[ks], S1, 0, 0, 0);
    }
    __builtin_amdgcn_s_setprio(0);

    const float a0 = vmax3(S0[0],  S0[1],  S0[2]);
    const float a1 = vmax3(S0[3],  S0[4],  S0[5]);
    const float a2 = vmax3(S0[6],  S0[7],  S0[8]);
    const float a3 = vmax3(S0[9],  S0[10], S0[11]);
    const float a4 = vmax3(S0[12], S0[13], S0[14]);
    const float b0 = vmax3(S1[0],  S1[1],  S1[2]);
    const float b1 = vmax3(S1[3],  S1[4],  S1[5]);
    const float b2 = vmax3(S1[6],  S1[7],  S1[8]);
    const float b3 = vmax3(S1[9],  S1[10], S1[11]);
    const float b4 = vmax3(S1[12], S1[13], S1[14]);
    const float c0 = vmax3(a0, a1, a2);
    const float c1 = vmax3(a3, a4, S0[15]);
    const float c2 = vmax3(b0, b1, b2);
    const float c3 = vmax3(b3, b4, S1[15]);
    const float mx = fmaxf(vmax3(c0, c1, c2), c3);

    if (__all((mrun == 0.0f) & (mx <= 30.0f))) {
#pragma unroll
      for (int i = 0; i < 16; ++i) {
        S0[i] = __builtin_amdgcn_exp2f(S0[i]);
        S1[i] = __builtin_amdgcn_exp2f(S1[i]);
      }
      lpv += S0 + S1;
    } else {
      const float om = fmaxf(mx, __shfl_xor(mx, 32));
      const float nm = fmaxf(mrun, om);
      const float scl = __builtin_amdgcn_exp2f(mrun - nm);
      mrun = nm;
#pragma unroll
      for (int i = 0; i < 16; ++i) {
        S0[i] = __builtin_amdgcn_exp2f(S0[i] - nm);
        S1[i] = __builtin_amdgcn_exp2f(S1[i] - nm);
      }
      lpv = lpv * scl + (S0 + S1);
      Oa0 = Oa0 * scl;
      Oa1 = Oa1 * scl;
    }

#pragma unroll
    for (int half = 0; half < 2; ++half) {
      unsigned hx[4], hy[4], lx[4], ly[4];
#pragma unroll
      for (int m = 0; m < 4; ++m) {
        float p0, p1, p2, p3;
        if (half == 0) { p0 = S0[4*m]; p1 = S0[4*m+1]; p2 = S0[4*m+2]; p3 = S0[4*m+3]; }
        else           { p0 = S1[4*m]; p1 = S1[4*m+1]; p2 = S1[4*m+2]; p3 = S1[4*m+3]; }
        bsplit2(p0, p1, hx[m], lx[m]);
        bsplit2(p2, p3, hy[m], ly[m]);
      }
      __builtin_amdgcn_s_setprio(1);
#pragma unroll
      for (int kss = 0; kss < 2; ++kss) {
        const i32x2v rhx = pl32(hx[2*kss], hx[2*kss+1]);
        const i32x2v rhy = pl32(hy[2*kss], hy[2*kss+1]);
        const i32x2v rlx = pl32(lx[2*kss], lx[2*kss+1]);
        const i32x2v rly = pl32(ly[2*kss], ly[2*kss+1]);
        v8u bfh, bfl;
        bfh.u[0] = (unsigned)rhx[0]; bfh.u[1] = (unsigned)rhy[0];
        bfh.u[2] = (unsigned)rhx[1]; bfh.u[3] = (unsigned)rhy[1];
        bfl.u[0] = (unsigned)rlx[0]; bfl.u[1] = (unsigned)rly[0];
        bfl.u[2] = (unsigned)rlx[1]; bfl.u[3] = (unsigned)rly[1];
        const int cc = ((4*half + 2*kss + l1) ^ (l31 & 7)) * 8;
        const short8v v0h = *(const short8v*)&VHs[cur][l31][cc];
        const short8v v0l = *(const short8v*)&VLs[cur][l31][cc];
        const short8v v1h = *(const short8v*)&VHs[cur][32 + l31][cc];
        const short8v v1l = *(const short8v*)&VLs[cur][32 + l31][cc];
        Oa0 = __builtin_amdgcn_mfma_f32_32x32x16_bf16(v0h, bfh.v, Oa0, 0, 0, 0);
        Oa1 = __builtin_amdgcn_mfma_f32_32x32x16_bf16(v1h, bfh.v, Oa1, 0, 0, 0);
        Oa0 = __builtin_amdgcn_mfma_f32_32x32x16_bf16(v0l, bfh.v, Oa0, 0, 0, 0);
        Oa1 = __builtin_amdgcn_mfma_f32_32x32x16_bf16(v1l, bfh.v, Oa1, 0, 0, 0);
        Oa0 = __builtin_amdgcn_mfma_f32_32x32x16_bf16(v0h, bfl.v, Oa0, 0, 0, 0);
        Oa1 = __builtin_amdgcn_mfma_f32_32x32x16_bf16(v1h, bfl.v, Oa1, 0, 0, 0);
      }
      __builtin_amdgcn_s_setprio(0);
    }
  }

  float lp = ((((lpv[0]+lpv[1])+(lpv[2]+lpv[3]))+((lpv[4]+lpv[5])+(lpv[6]+lpv[7])))
           + (((lpv[8]+lpv[9])+(lpv[10]+lpv[11]))+((lpv[12]+lpv[13])+(lpv[14]+lpv[15]))));
  lp += __shfl_xor(lp, 32);
  const float inv = 1.0f / lp;
  const size_t orow = ((size_t)n * SEQ + qt * 256 + w * 32 + l31) * DMODEL + h * HDIM;
#pragma unroll
  for (int jd = 0; jd < 2; ++jd) {
#pragma unroll
    for (int g = 0; g < 4; ++g) {
      float o0, o1, o2, o3;
      if (jd == 0) { o0 = Oa0[4*g]; o1 = Oa0[4*g+1]; o2 = Oa0[4*g+2]; o3 = Oa0[4*g+3]; }
      else         { o0 = Oa1[4*g]; o1 = Oa1[4*g+1]; o2 = Oa1[4*g+2]; o3 = Oa1[4*g+3]; }
      o0 *= inv; o1 *= inv; o2 *= inv; o3 *= inv;
      unsigned h01, l01, h23, l23;
      bsplit2(o0, o1, h01, l01);
      bsplit2(o2, o3, h23, l23);
      const int d = 32 * jd + 8 * g + 4 * l1;
      uint2 sh; sh.x = h01; sh.y = h23;
      uint2 sl; sl.x = l01; sl.y = l23;
      *(uint2*)&abh[orow + d] = sh;
      *(uint2*)&abl[orow + d] = sl;
    }
  }
#undef ATTN_ISSUE
}

// ---------------------------------------------------------------------------
extern "C" void kernel_launch(void* const* d_in, const int* in_sizes, int n_in,
                              void* d_out, int out_size, void* d_ws, size_t ws_size,
                              hipStream_t stream) {
  (void)in_sizes; (void)n_in; (void)out_size;
  const float* Xq  = (const float*)d_in[0];
  const float* Xkv = (const float*)d_in[1];
  const float* Wq  = (const float*)d_in[2];
  const float* bq  = (const float*)d_in[3];
  const float* Wk  = (const float*)d_in[4];
  const float* bk  = (const float*)d_in[5];
  const float* Wv  = (const float*)d_in[6];
  const float* bv  = (const float*)d_in[7];
  const float* Wo  = (const float*)d_in[8];
  const float* bo  = (const float*)d_in[9];
  float* out = (float*)d_out;

  if (ws_size < 201588736ull) return;
  char* W = (char*)d_ws;
  const size_t HB = 25165824ull;
  float*    rope = (float*)W;
  ushort_t* vth = (ushort_t*)(W + 262144);
  ushort_t* vtl = (ushort_t*)(W + 262144 + HB);
  char* C0 = W + 262144 + 2 * HB;
  ushort_t* qhi = (ushort_t*)(C0);
  ushort_t* qlo = (ushort_t*)(C0 + HB);
  ushort_t* khi = (ushort_t*)(C0 + 2 * HB);
  ushort_t* klo = (ushort_t*)(C0 + 3 * HB);
  ushort_t* woth = (ushort_t*)(C0);
  ushort_t* wotl = woth + 589824;
  char* D0 = C0 + 4 * HB;
  ushort_t* abh = (ushort_t*)(D0);
  ushort_t* abl = (ushort_t*)(D0 + HB);
  ushort_t* wqth = (ushort_t*)d_out;            ushort_t* wqtl = wqth + 589824;
  ushort_t* wkth = wqth + 1179648;              ushort_t* wktl = wkth + 589824;
  ushort_t* wvth = wqth + 2359296;              ushort_t* wvtl = wvth + 589824;

  prep_kernel<<<496, 256, 0, stream>>>(rope, Wq, wqth, wqtl, Wk, wkth, wktl, Wv, wvth, wvtl);

  const dim3 gg(DMODEL / 128, MTOT / 128);   // x = N-tile, y = M-tile
  const float q_scale = 0.125f * 1.44269504088896340736f;   // (1/8)*log2(e)

  gemm_mfma_kernel<1,0><<<gg, 256, 0, stream>>>(Xq, nullptr, nullptr, wqth, wqtl,
                                                bq, nullptr, qhi, qlo, rope, 1, q_scale);
  gemm_mfma_kernel<1,0><<<gg, 256, 0, stream>>>(Xkv, nullptr, nullptr, wkth, wktl,
                                                bk, nullptr, khi, klo, rope, 1, 1.0f);
  gemm_mfma_kernel<1,1><<<gg, 256, 0, stream>>>(Xkv, nullptr, nullptr, wvth, wvtl,
                                                bv, nullptr, vth, vtl, rope, 2, 1.0f);

  attn_mfma_kernel<<<768, 512, 0, stream>>>(qhi, qlo, khi, klo, vth, vtl, abh, abl);

  wsplit_t_kernel<<<dim3(12, 12), 256, 0, stream>>>(Wo, woth, wotl);
  gemm_mfma_kernel<0,0><<<gg, 256, 0, stream>>>(nullptr, abh, abl, woth, wotl,
                                                bo, out, nullptr, nullptr, rope, 0, 1.0f);
}

// Round 16
// 486.243 us; speedup vs baseline: 1.0970x; 1.0970x over previous
//
#include <hip/hip_runtime.h>
#include <cmath>

#define DMODEL 768
#define SEQ    1024
#define NH     12
#define HDIM   64
#define MTOT   16384   // 16 * 1024

typedef unsigned short ushort_t;
typedef __attribute__((ext_vector_type(8))) short short8v;
typedef __attribute__((ext_vector_type(4))) float f32x4;
typedef __attribute__((ext_vector_type(16))) float f32x16;
typedef __attribute__((ext_vector_type(2))) int i32x2v;

union v8u { short8v v; unsigned u[4]; };

__device__ __forceinline__ ushort_t bf16rn(float x) {
  unsigned u = __float_as_uint(x);
  return (ushort_t)((u + 0x7FFFu + ((u >> 16) & 1u)) >> 16);
}
__device__ __forceinline__ void bsplit(float x, ushort_t& h, ushort_t& l) {
  h = bf16rn(x);
  float hf = __uint_as_float((unsigned)h << 16);
  l = bf16rn(x - hf);
}

__device__ __forceinline__ unsigned cvt_pk_bf16(float a, float b) {
  unsigned r;
  asm("v_cvt_pk_bf16_f32 %0, %1, %2" : "=v"(r) : "v"(a), "v"(b));
  return r;
}
__device__ __forceinline__ void bsplit2(float x0, float x1, unsigned& hw, unsigned& lw) {
  hw = cvt_pk_bf16(x0, x1);
  const float h0 = __uint_as_float(hw << 16);
  const float h1 = __uint_as_float(hw & 0xFFFF0000u);
  lw = cvt_pk_bf16(x0 - h0, x1 - h1);
}

__device__ __forceinline__ float vmax3(float a, float b, float c) {
  float d;
  asm("v_max3_f32 %0, %1, %2, %3" : "=v"(d) : "v"(a), "v"(b), "v"(c));
  return d;
}

__device__ __forceinline__ i32x2v pl32(unsigned a, unsigned b) {
  return __builtin_amdgcn_permlane32_swap((int)a, (int)b, false, false);
}

__device__ __forceinline__ void gld16(const void* g, void* l) {
  __builtin_amdgcn_global_load_lds(
      (const __attribute__((address_space(1))) int*)g,
      (__attribute__((address_space(3))) int*)l, 16, 0, 0);
}

// ---------------------------------------------------------------------------
// Weight transpose+split body: W [768k][768n] fp32 -> hi/lo bf16 [768n][768k]
// ---------------------------------------------------------------------------
__device__ __forceinline__
void wsplit_body(const float* __restrict__ W, ushort_t* __restrict__ TH,
                 ushort_t* __restrict__ TL, int kt, int nt, int t, float* Tls) {
  float (*T)[65] = (float(*)[65])Tls;
  const int r = t >> 2, c4 = (t & 3) * 16;
  const float* src = W + (size_t)(kt * 64 + r) * DMODEL + nt * 64 + c4;
#pragma unroll
  for (int i = 0; i < 16; i += 4)
    *(float4*)&T[r][c4 + i] = *(const float4*)&src[i];
  __syncthreads();
  short8v h0, h1, l0, l1;
#pragma unroll
  for (int i = 0; i < 8; ++i) {
    ushort_t hh, ll;
    bsplit(T[c4 + i][r], hh, ll);
    h0[i] = (short)hh; l0[i] = (short)ll;
  }
#pragma unroll
  for (int i = 0; i < 8; ++i) {
    ushort_t hh, ll;
    bsplit(T[c4 + 8 + i][r], hh, ll);
    h1[i] = (short)hh; l1[i] = (short)ll;
  }
  const size_t o = (size_t)(nt * 64 + r) * DMODEL + kt * 64 + c4;
  *(short8v*)&TH[o] = h0; *(short8v*)&TH[o + 8] = h1;
  *(short8v*)&TL[o] = l0; *(short8v*)&TL[o + 8] = l1;
}

// ---------------------------------------------------------------------------
// Prep kernel: blocks 0..63 = RoPE tables; 64.. = Wq/Wk/Wv transpose+split
// ---------------------------------------------------------------------------
__global__ __launch_bounds__(256)
void prep_kernel(float* __restrict__ tab,
                 const float* __restrict__ Wq, ushort_t* __restrict__ QH, ushort_t* __restrict__ QL,
                 const float* __restrict__ Wk, ushort_t* __restrict__ KH, ushort_t* __restrict__ KL,
                 const float* __restrict__ Wv, ushort_t* __restrict__ VH, ushort_t* __restrict__ VL) {
  __shared__ __align__(16) float Tls[64 * 65];
  const int bx = blockIdx.x, t = threadIdx.x;
  if (bx < 64) {
    int idx = bx * 256 + t;
    int l = idx >> 4, p = idx & 15;
    double u = ((double)(l & 31) + 0.5) / 32.0;
    double v = ((double)(l >> 5) + 0.5) / 32.0;
    double freq = (double)p / (15.0 + 1e-9);
    double inv = pow(10000.0, -freq);
    tab[idx]         = (float)cos(u * inv);
    tab[16384 + idx] = (float)sin(u * inv);
    tab[32768 + idx] = (float)cos(v * inv);
    tab[49152 + idx] = (float)sin(v * inv);
    return;
  }
  const int wi = (bx - 64) / 144, b = (bx - 64) % 144;
  const int kt = b % 12, nt = b / 12;
  if (wi == 0)      wsplit_body(Wq, QH, QL, kt, nt, t, Tls);
  else if (wi == 1) wsplit_body(Wk, KH, KL, kt, nt, t, Tls);
  else              wsplit_body(Wv, VH, VL, kt, nt, t, Tls);
}

// standalone wsplit for Wo (must run after attn: output aliases q-buffers)
__global__ __launch_bounds__(256)
void wsplit_t_kernel(const float* __restrict__ W, ushort_t* __restrict__ TH,
                     ushort_t* __restrict__ TL) {
  __shared__ __align__(16) float Tls[64 * 65];
  wsplit_body(W, TH, TL, blockIdx.x, blockIdx.y, threadIdx.x, Tls);
}

// ---------------------------------------------------------------------------
// Fused QKV GEMM: one launch, blockIdx.z = {0:Q, 1:K, 2:V}.
// A fp32 staged swizzled + split in-register (bit-identical to pre-split).
// z<2: RoPE epilogue (+oscale), per-head hi/lo. z==2: fused V^T epilogue.
// ---------------------------------------------------------------------------
__global__ __launch_bounds__(256)
void qkv_gemm_kernel(const float* __restrict__ Xq, const float* __restrict__ Xkv,
                     const ushort_t* __restrict__ QWh, const ushort_t* __restrict__ QWl,
                     const ushort_t* __restrict__ KWh, const ushort_t* __restrict__ KWl,
                     const ushort_t* __restrict__ VWh, const ushort_t* __restrict__ VWl,
                     const float* __restrict__ bq, const float* __restrict__ bk,
                     const float* __restrict__ bv,
                     ushort_t* __restrict__ qhi, ushort_t* __restrict__ qlo,
                     ushort_t* __restrict__ khi, ushort_t* __restrict__ klo,
                     ushort_t* __restrict__ vth, ushort_t* __restrict__ vtl,
                     const float* __restrict__ rope, float q_scale) {
  __shared__ __align__(16) unsigned char Araw[16384];   // fp32 A tile
  __shared__ __align__(16) ushort_t Bh[128][32];
  __shared__ __align__(16) ushort_t Bl[128][32];
  float* Afs = (float*)Araw;

  const int z = blockIdx.z;
  const float* Af = (z == 0) ? Xq : Xkv;
  const ushort_t* Bhi = (z == 0) ? QWh : (z == 1) ? KWh : VWh;
  const ushort_t* Blo = (z == 0) ? QWl : (z == 1) ? KWl : VWl;
  const float* bias = (z == 0) ? bq : (z == 1) ? bk : bv;
  ushort_t* Ohi = (z == 0) ? qhi : (z == 1) ? khi : vth;
  ushort_t* Olo = (z == 0) ? qlo : (z == 1) ? klo : vtl;
  const float oscale = (z == 0) ? q_scale : 1.0f;

  const int t = threadIdx.x, lane = t & 63, w = t >> 6;
  const int l15 = lane & 15, l4 = lane >> 4;
  const int wm = w >> 1, wn = w & 1;
  const int m0 = blockIdx.y * 128, n0 = blockIdx.x * 128;

  const int crow = t >> 2, ccc = (t & 3) * 8;
  const ushort_t* pBh0 = Bhi + (size_t)(n0 + crow) * DMODEL + ccc;
  const ushort_t* pBh1 = pBh0 + (size_t)64 * DMODEL;
  const ushort_t* pBl0 = Blo + (size_t)(n0 + crow) * DMODEL + ccc;
  const ushort_t* pBl1 = pBl0 + (size_t)64 * DMODEL;
  void* dBh0 = &Bh[crow][ccc];      void* dBh1 = &Bh[crow + 64][ccc];
  void* dBl0 = &Bl[crow][ccc];      void* dBl1 = &Bl[crow + 64][ccc];

  const int sr8 = lane >> 3, sc8 = lane & 7, sg = sc8 ^ sr8;

  f32x4 acc[4][4] = {};

  for (int ks = 0; ks < DMODEL / 32; ++ks) {
    __syncthreads();
#pragma unroll
    for (int j = 0; j < 4; ++j) {
      const int row = j * 32 + w * 8 + sr8;
      gld16(Af + (size_t)(m0 + row) * DMODEL + ks * 32 + sg * 4,
            &Afs[row * 32 + sc8 * 4]);
    }
    gld16(pBh0, dBh0); gld16(pBh1, dBh1);
    gld16(pBl0, dBl0); gld16(pBl1, dBl1);
    pBh0 += 32; pBh1 += 32; pBl0 += 32; pBl1 += 32;
    __syncthreads();

    short8v afh[4], afl[4], bfh[4], bfl[4];
#pragma unroll
    for (int f = 0; f < 4; ++f) {
      const int row = wm * 64 + f * 16 + l15;
      const int rs = l15 & 7;
      const float* ap = Afs + row * 32;
      const f32x4 x0 = *(const f32x4*)(ap + (((2 * l4)     ^ rs) * 4));
      const f32x4 x1 = *(const f32x4*)(ap + (((2 * l4 + 1) ^ rs) * 4));
      v8u hh, ll;
      bsplit2(x0[0], x0[1], hh.u[0], ll.u[0]);
      bsplit2(x0[2], x0[3], hh.u[1], ll.u[1]);
      bsplit2(x1[0], x1[1], hh.u[2], ll.u[2]);
      bsplit2(x1[2], x1[3], hh.u[3], ll.u[3]);
      afh[f] = hh.v; afl[f] = ll.v;
      bfh[f] = *(const short8v*)&Bh[wn * 64 + f * 16 + l15][l4 * 8];
      bfl[f] = *(const short8v*)&Bl[wn * 64 + f * 16 + l15][l4 * 8];
    }
#pragma unroll
    for (int mf = 0; mf < 4; ++mf)
#pragma unroll
      for (int nf = 0; nf < 4; ++nf) {
        acc[mf][nf] = __builtin_amdgcn_mfma_f32_16x16x32_bf16(afh[mf], bfh[nf], acc[mf][nf], 0, 0, 0);
        acc[mf][nf] = __builtin_amdgcn_mfma_f32_16x16x32_bf16(afl[mf], bfh[nf], acc[mf][nf], 0, 0, 0);
        acc[mf][nf] = __builtin_amdgcn_mfma_f32_16x16x32_bf16(afh[mf], bfl[nf], acc[mf][nf], 0, 0, 0);
      }
  }

  float bcol[4];
#pragma unroll
  for (int nf = 0; nf < 4; ++nf) bcol[nf] = bias[n0 + wn * 64 + nf * 16 + l15];

  if (z == 2) {
    // fused V^T epilogue (identical to R14 VT path)
    ushort_t* hiT = (ushort_t*)Araw;
    ushort_t* loTa = (ushort_t*)Bh;
    ushort_t* loTb = (ushort_t*)Bl;
    const int nb = blockIdx.y >> 3;
    const int l0 = (blockIdx.y & 7) * 128;
#pragma unroll
    for (int hs = 0; hs < 2; ++hs) {
      __syncthreads();
      if (wn == hs) {
#pragma unroll
        for (int mf = 0; mf < 4; ++mf)
#pragma unroll
          for (int r = 0; r < 4; ++r) {
            const int ll = wm * 64 + mf * 16 + l4 * 4 + r;
            const int lg = ll >> 3, li = ll & 7;
            unsigned h01, lo01, h23, lo23;
            bsplit2(acc[mf][0][r] + bcol[0], acc[mf][1][r] + bcol[1], h01, lo01);
            bsplit2(acc[mf][2][r] + bcol[2], acc[mf][3][r] + bcol[3], h23, lo23);
            const ushort_t hv[4] = {(ushort_t)(h01 & 0xFFFFu), (ushort_t)(h01 >> 16),
                                    (ushort_t)(h23 & 0xFFFFu), (ushort_t)(h23 >> 16)};
            const ushort_t lv[4] = {(ushort_t)(lo01 & 0xFFFFu), (ushort_t)(lo01 >> 16),
                                    (ushort_t)(lo23 & 0xFFFFu), (ushort_t)(lo23 >> 16)};
#pragma unroll
            for (int nf = 0; nf < 4; ++nf) {
              const int d = nf * 16 + l15;
              const int off = ((lg ^ (d & 7)) << 3) + li;
              hiT[d * 128 + off] = hv[nf];
              if (nf < 2) loTa[d * 128 + off] = lv[nf];
              else        loTb[(d - 32) * 128 + off] = lv[nf];
            }
          }
      }
      __syncthreads();
      {
        const int d = t >> 2;
        const int hglob = blockIdx.x * 2 + hs;
        const size_t dst = ((size_t)(nb * NH + hglob) * HDIM + d) * SEQ + l0;
#pragma unroll
        for (int j = 0; j < 4; ++j) {
          const int lg = (t & 3) * 4 + j;
          const int off = (lg ^ (d & 7)) << 3;
          const short8v hv = *(const short8v*)&hiT[d * 128 + off];
          const short8v lv = (d < 32) ? *(const short8v*)&loTa[d * 128 + off]
                                      : *(const short8v*)&loTb[(d - 32) * 128 + off];
          *(short8v*)&Ohi[dst + lg * 8] = hv;
          *(short8v*)&Olo[dst + lg * 8] = lv;
        }
      }
    }
  } else {
    const int h = blockIdx.x * 2 + wn;
#pragma unroll
    for (int mf = 0; mf < 4; ++mf)
#pragma unroll
      for (int r = 0; r < 4; ++r) {
        const int m = m0 + wm * 64 + mf * 16 + l4 * 4 + r;
        const int l = m & (SEQ - 1);
        const int nb = m >> 10;
        const size_t orow = ((size_t)(nb * NH + h) * SEQ + l) * HDIM;
        float vv[4];
#pragma unroll
        for (int nf = 0; nf < 4; ++nf) {
          float v = acc[mf][nf][r] + bcol[nf];
          const float vp = __shfl_xor(v, 1, 64);
          const int tb = (nf < 2) ? 0 : 32768;
          const int pi = (nf & 1) * 8 + (l15 >> 1);
          const float c = rope[tb + l * 16 + pi];
          const float s = rope[tb + 16384 + l * 16 + pi];
          v = (l15 & 1) ? (vp * s + v * c) : (v * c - vp * s);
          v *= oscale;   // Q: log2e/8 (exp2-domain); K: 1.0
          vv[nf] = v;
        }
        unsigned h01, l01, h23, l23;
        bsplit2(vv[0], vv[1], h01, l01);
        bsplit2(vv[2], vv[3], h23, l23);
        Ohi[orow + 0 * 16 + l15] = (ushort_t)(h01 & 0xFFFFu);
        Ohi[orow + 1 * 16 + l15] = (ushort_t)(h01 >> 16);
        Ohi[orow + 2 * 16 + l15] = (ushort_t)(h23 & 0xFFFFu);
        Ohi[orow + 3 * 16 + l15] = (ushort_t)(h23 >> 16);
        Olo[orow + 0 * 16 + l15] = (ushort_t)(l01 & 0xFFFFu);
        Olo[orow + 1 * 16 + l15] = (ushort_t)(l01 >> 16);
        Olo[orow + 2 * 16 + l15] = (ushort_t)(l23 & 0xFFFFu);
        Olo[orow + 3 * 16 + l15] = (ushort_t)(l23 >> 16);
      }
  }
}

// ---------------------------------------------------------------------------
// Final projection GEMM (pre-split bf16 A, fp32 C) — unchanged R14 structure.
// ---------------------------------------------------------------------------
__global__ __launch_bounds__(256)
void out_gemm_kernel(const ushort_t* __restrict__ Ahi, const ushort_t* __restrict__ Alo,
                     const ushort_t* __restrict__ Bhi, const ushort_t* __restrict__ Blo,
                     const float* __restrict__ bias, float* __restrict__ Cout) {
  __shared__ __align__(16) ushort_t Ah[128][32];
  __shared__ __align__(16) ushort_t Al[128][32];
  __shared__ __align__(16) ushort_t Bh[128][32];
  __shared__ __align__(16) ushort_t Bl[128][32];

  const int t = threadIdx.x, lane = t & 63, w = t >> 6;
  const int l15 = lane & 15, l4 = lane >> 4;
  const int wm = w >> 1, wn = w & 1;
  const int m0 = blockIdx.y * 128, n0 = blockIdx.x * 128;

  const int crow = t >> 2, ccc = (t & 3) * 8;
  const ushort_t* pAh0 = Ahi + (size_t)(m0 + crow) * DMODEL + ccc;
  const ushort_t* pAh1 = pAh0 + (size_t)64 * DMODEL;
  const ushort_t* pAl0 = Alo + (size_t)(m0 + crow) * DMODEL + ccc;
  const ushort_t* pAl1 = pAl0 + (size_t)64 * DMODEL;
  const ushort_t* pBh0 = Bhi + (size_t)(n0 + crow) * DMODEL + ccc;
  const ushort_t* pBh1 = pBh0 + (size_t)64 * DMODEL;
  const ushort_t* pBl0 = Blo + (size_t)(n0 + crow) * DMODEL + ccc;
  const ushort_t* pBl1 = pBl0 + (size_t)64 * DMODEL;
  void* dAh0 = &Ah[crow][ccc];      void* dAh1 = &Ah[crow + 64][ccc];
  void* dAl0 = &Al[crow][ccc];      void* dAl1 = &Al[crow + 64][ccc];
  void* dBh0 = &Bh[crow][ccc];      void* dBh1 = &Bh[crow + 64][ccc];
  void* dBl0 = &Bl[crow][ccc];      void* dBl1 = &Bl[crow + 64][ccc];

  f32x4 acc[4][4] = {};

  for (int ks = 0; ks < DMODEL / 32; ++ks) {
    __syncthreads();
    gld16(pAh0, dAh0); gld16(pAh1, dAh1);
    gld16(pAl0, dAl0); gld16(pAl1, dAl1);
    gld16(pBh0, dBh0); gld16(pBh1, dBh1);
    gld16(pBl0, dBl0); gld16(pBl1, dBl1);
    pAh0 += 32; pAh1 += 32; pAl0 += 32; pAl1 += 32;
    pBh0 += 32; pBh1 += 32; pBl0 += 32; pBl1 += 32;
    __syncthreads();

    short8v afh[4], afl[4], bfh[4], bfl[4];
#pragma unroll
    for (int f = 0; f < 4; ++f) {
      afh[f] = *(const short8v*)&Ah[wm * 64 + f * 16 + l15][l4 * 8];
      afl[f] = *(const short8v*)&Al[wm * 64 + f * 16 + l15][l4 * 8];
      bfh[f] = *(const short8v*)&Bh[wn * 64 + f * 16 + l15][l4 * 8];
      bfl[f] = *(const short8v*)&Bl[wn * 64 + f * 16 + l15][l4 * 8];
    }
#pragma unroll
    for (int mf = 0; mf < 4; ++mf)
#pragma unroll
      for (int nf = 0; nf < 4; ++nf) {
        acc[mf][nf] = __builtin_amdgcn_mfma_f32_16x16x32_bf16(afh[mf], bfh[nf], acc[mf][nf], 0, 0, 0);
        acc[mf][nf] = __builtin_amdgcn_mfma_f32_16x16x32_bf16(afl[mf], bfh[nf], acc[mf][nf], 0, 0, 0);
        acc[mf][nf] = __builtin_amdgcn_mfma_f32_16x16x32_bf16(afh[mf], bfl[nf], acc[mf][nf], 0, 0, 0);
      }
  }

  float bcol[4];
#pragma unroll
  for (int nf = 0; nf < 4; ++nf) bcol[nf] = bias[n0 + wn * 64 + nf * 16 + l15];

#pragma unroll
  for (int mf = 0; mf < 4; ++mf)
#pragma unroll
    for (int r = 0; r < 4; ++r) {
      const int m = m0 + wm * 64 + mf * 16 + l4 * 4 + r;
#pragma unroll
      for (int nf = 0; nf < 4; ++nf)
        Cout[(size_t)m * DMODEL + n0 + wn * 64 + nf * 16 + l15] = acc[mf][nf][r] + bcol[nf];
    }
}

// ---------------------------------------------------------------------------
// Flash attention (R15 config, unchanged): QBLK=256 / 8 waves, 32x32x16 MFMA,
// swapped QK^T, permlane32_swap P-redistribution, K+V double-buffered via
// global_load_lds + pre-swizzled source, 1 barrier/kt, 64 KB LDS.
// ---------------------------------------------------------------------------
__global__ __launch_bounds__(512)
void attn_mfma_kernel(const ushort_t* __restrict__ qh, const ushort_t* __restrict__ ql,
                      const ushort_t* __restrict__ kh, const ushort_t* __restrict__ kl,
                      const ushort_t* __restrict__ vth, const ushort_t* __restrict__ vtl,
                      ushort_t* __restrict__ abh, ushort_t* __restrict__ abl) {
  __shared__ __align__(16) ushort_t KHs[2][64][64];
  __shared__ __align__(16) ushort_t KLs[2][64][64];
  __shared__ __align__(16) ushort_t VHs[2][64][64];
  __shared__ __align__(16) ushort_t VLs[2][64][64];

  const int t = threadIdx.x;
  const int lane = t & 63, w = t >> 6;       // 8 waves
  const int l31 = lane & 31, l1 = lane >> 5;

  const int bid = blockIdx.x;                // 768 blocks
  const int xcd = bid & 7, rest = bid >> 3;
  const int qt = rest & 3;                   // 4 q-tiles of 256 rows
  const int hl = (rest >> 2) * 8 + xcd;      // head pinned to XCD
  const int h = hl % NH, n = hl / NH;

  const size_t base = (size_t)(n * NH + h) * (SEQ * HDIM);

  short8v qfh[4], qfl[4];
  {
    const size_t qoff = base + (size_t)(qt * 256 + w * 32 + l31) * HDIM + l1 * 8;
#pragma unroll
    for (int ks = 0; ks < 4; ++ks) {
      qfh[ks] = *(const short8v*)&qh[qoff + ks * 16];
      qfl[ks] = *(const short8v*)&ql[qoff + ks * 16];
    }
  }

  const int srow = lane >> 3;
  const int schk = (lane & 7) ^ srow;
  const size_t kof = base + (size_t)(w * 8 + srow) * HDIM + schk * 8;
  const size_t vof = base + (size_t)(w * 8 + srow) * SEQ + schk * 8;
  const int dr = w * 8 + srow, dc = (lane & 7) * 8;

  f32x16 Oa0 = {}, Oa1 = {};
  f32x16 lpv = {};
  float mrun = 0.0f;

#define ATTN_ISSUE(kt_, b_) do {                                            \
    const size_t ko_ = (size_t)(kt_) * (64 * HDIM);                         \
    const size_t vo_ = (size_t)(kt_) * 64;                                  \
    gld16(kh  + kof + ko_, &KHs[b_][dr][dc]);                               \
    gld16(kl  + kof + ko_, &KLs[b_][dr][dc]);                               \
    gld16(vth + vof + vo_, &VHs[b_][dr][dc]);                               \
    gld16(vtl + vof + vo_, &VLs[b_][dr][dc]);                               \
  } while (0)

  ATTN_ISSUE(0, 0);

  for (int kt = 0; kt < 16; ++kt) {
    const int cur = kt & 1;
    __syncthreads();
    if (kt < 15) ATTN_ISSUE(kt + 1, cur ^ 1);

    f32x16 S0 = {}, S1 = {};
    __builtin_amdgcn_s_setprio(1);
#pragma unroll
    for (int ks = 0; ks < 4; ++ks) {
      const int cc = ((2 * ks + l1) ^ (l31 & 7)) * 8;
      const short8v k0h = *(const short8v*)&KHs[cur][l31][cc];
      const short8v k0l = *(const short8v*)&KLs[cur][l31][cc];
      const short8v k1h = *(const short8v*)&KHs[cur][32 + l31][cc];
      const short8v k1l = *(const short8v*)&KLs[cur][32 + l31][cc];
      S0 = __builtin_amdgcn_mfma_f32_32x32x16_bf16(k0h, qfh[ks], S0, 0, 0, 0);
      S1 = __builtin_amdgcn_mfma_f32_32x32x16_bf16(k1h, qfh[ks], S1, 0, 0, 0);
      S0 = __builtin_amdgcn_mfma_f32_32x32x16_bf16(k0l, qfh[ks], S0, 0, 0, 0);
      S1 = __builtin_amdgcn_mfma_f32_32x32x16_bf16(k1l, qfh[ks], S1, 0, 0, 0);
      S0 = __builtin_amdgcn_mfma_f32_32x32x16_bf16(k0h, qfl[ks], S0, 0, 0, 0);
      S1 = __builtin_amdgcn_mfma_f32_32x32x16_bf16(k1h, qfl[ks], S1, 0, 0, 0);
    }
    __builtin_amdgcn_s_setprio(0);

    const float a0 = vmax3(S0[0],  S0[1],  S0[2]);
    const float a1 = vmax3(S0[3],  S0[4],  S0[5]);
    const float a2 = vmax3(S0[6],  S0[7],  S0[8]);
    const float a3 = vmax3(S0[9],  S0[10], S0[11]);
    const float a4 = vmax3(S0[12], S0[13], S0[14]);
    const float b0 = vmax3(S1[0],  S1[1],  S1[2]);
    const float b1 = vmax3(S1[3],  S1[4],  S1[5]);
    const float b2 = vmax3(S1[6],  S1[7],  S1[8]);
    const float b3 = vmax3(S1[9],  S1[10], S1[11]);
    const float b4 = vmax3(S1[12], S1[13], S1[14]);
    const float c0 = vmax3(a0, a1, a2);
    const float c1 = vmax3(a3, a4, S0[15]);
    const float c2 = vmax3(b0, b1, b2);
    const float c3 = vmax3(b3, b4, S1[15]);
    const float mx = fmaxf(vmax3(c0, c1, c2), c3);

    if (__all((mrun == 0.0f) & (mx <= 30.0f))) {
#pragma unroll
      for (int i = 0; i < 16; ++i) {
        S0[i] = __builtin_amdgcn_exp2f(S0[i]);
        S1[i] = __builtin_amdgcn_exp2f(S1[i]);
      }
      lpv += S0 + S1;
    } else {
      const float om = fmaxf(mx, __shfl_xor(mx, 32));
      const float nm = fmaxf(mrun, om);
      const float scl = __builtin_amdgcn_exp2f(mrun - nm);
      mrun = nm;
#pragma unroll
      for (int i = 0; i < 16; ++i) {
        S0[i] = __builtin_amdgcn_exp2f(S0[i] - nm);
        S1[i] = __builtin_amdgcn_exp2f(S1[i] - nm);
      }
      lpv = lpv * scl + (S0 + S1);
      Oa0 = Oa0 * scl;
      Oa1 = Oa1 * scl;
    }

#pragma unroll
    for (int half = 0; half < 2; ++half) {
      unsigned hx[4], hy[4], lx[4], ly[4];
#pragma unroll
      for (int m = 0; m < 4; ++m) {
        float p0, p1, p2, p3;
        if (half == 0) { p0 = S0[4*m]; p1 = S0[4*m+1]; p2 = S0[4*m+2]; p3 = S0[4*m+3]; }
        else           { p0 = S1[4*m]; p1 = S1[4*m+1]; p2 = S1[4*m+2]; p3 = S1[4*m+3]; }
        bsplit2(p0, p1, hx[m], lx[m]);
        bsplit2(p2, p3, hy[m], ly[m]);
      }
      __builtin_amdgcn_s_setprio(1);
#pragma unroll
      for (int kss = 0; kss < 2; ++kss) {
        const i32x2v rhx = pl32(hx[2*kss], hx[2*kss+1]);
        const i32x2v rhy = pl32(hy[2*kss], hy[2*kss+1]);
        const i32x2v rlx = pl32(lx[2*kss], lx[2*kss+1]);
        const i32x2v rly = pl32(ly[2*kss], ly[2*kss+1]);
        v8u bfh, bfl;
        bfh.u[0] = (unsigned)rhx[0]; bfh.u[1] = (unsigned)rhy[0];
        bfh.u[2] = (unsigned)rhx[1]; bfh.u[3] = (unsigned)rhy[1];
        bfl.u[0] = (unsigned)rlx[0]; bfl.u[1] = (unsigned)rly[0];
        bfl.u[2] = (unsigned)rlx[1]; bfl.u[3] = (unsigned)rly[1];
        const int cc = ((4*half + 2*kss + l1) ^ (l31 & 7)) * 8;
        const short8v v0h = *(const short8v*)&VHs[cur][l31][cc];
        const short8v v0l = *(const short8v*)&VLs[cur][l31][cc];
        const short8v v1h = *(const short8v*)&VHs[cur][32 + l31][cc];
        const short8v v1l = *(const short8v*)&VLs[cur][32 + l31][cc];
        Oa0 = __builtin_amdgcn_mfma_f32_32x32x16_bf16(v0h, bfh.v, Oa0, 0, 0, 0);
        Oa1 = __builtin_amdgcn_mfma_f32_32x32x16_bf16(v1h, bfh.v, Oa1, 0, 0, 0);
        Oa0 = __builtin_amdgcn_mfma_f32_32x32x16_bf16(v0l, bfh.v, Oa0, 0, 0, 0);
        Oa1 = __builtin_amdgcn_mfma_f32_32x32x16_bf16(v1l, bfh.v, Oa1, 0, 0, 0);
        Oa0 = __builtin_amdgcn_mfma_f32_32x32x16_bf16(v0h, bfl.v, Oa0, 0, 0, 0);
        Oa1 = __builtin_amdgcn_mfma_f32_32x32x16_bf16(v1h, bfl.v, Oa1, 0, 0, 0);
      }
      __builtin_amdgcn_s_setprio(0);
    }
  }

  float lp = ((((lpv[0]+lpv[1])+(lpv[2]+lpv[3]))+((lpv[4]+lpv[5])+(lpv[6]+lpv[7])))
           + (((lpv[8]+lpv[9])+(lpv[10]+lpv[11]))+((lpv[12]+lpv[13])+(lpv[14]+lpv[15]))));
  lp += __shfl_xor(lp, 32);
  const float inv = 1.0f / lp;
  const size_t orow = ((size_t)n * SEQ + qt * 256 + w * 32 + l31) * DMODEL + h * HDIM;
#pragma unroll
  for (int jd = 0; jd < 2; ++jd) {
#pragma unroll
    for (int g = 0; g < 4; ++g) {
      float o0, o1, o2, o3;
      if (jd == 0) { o0 = Oa0[4*g]; o1 = Oa0[4*g+1]; o2 = Oa0[4*g+2]; o3 = Oa0[4*g+3]; }
      else         { o0 = Oa1[4*g]; o1 = Oa1[4*g+1]; o2 = Oa1[4*g+2]; o3 = Oa1[4*g+3]; }
      o0 *= inv; o1 *= inv; o2 *= inv; o3 *= inv;
      unsigned h01, l01, h23, l23;
      bsplit2(o0, o1, h01, l01);
      bsplit2(o2, o3, h23, l23);
      const int d = 32 * jd + 8 * g + 4 * l1;
      uint2 sh; sh.x = h01; sh.y = h23;
      uint2 sl; sl.x = l01; sl.y = l23;
      *(uint2*)&abh[orow + d] = sh;
      *(uint2*)&abl[orow + d] = sl;
    }
  }
#undef ATTN_ISSUE
}

// ---------------------------------------------------------------------------
extern "C" void kernel_launch(void* const* d_in, const int* in_sizes, int n_in,
                              void* d_out, int out_size, void* d_ws, size_t ws_size,
                              hipStream_t stream) {
  (void)in_sizes; (void)n_in; (void)out_size;
  const float* Xq  = (const float*)d_in[0];
  const float* Xkv = (const float*)d_in[1];
  const float* Wq  = (const float*)d_in[2];
  const float* bq  = (const float*)d_in[3];
  const float* Wk  = (const float*)d_in[4];
  const float* bk  = (const float*)d_in[5];
  const float* Wv  = (const float*)d_in[6];
  const float* bv  = (const float*)d_in[7];
  const float* Wo  = (const float*)d_in[8];
  const float* bo  = (const float*)d_in[9];
  float* out = (float*)d_out;

  if (ws_size < 201588736ull) return;
  char* W = (char*)d_ws;
  const size_t HB = 25165824ull;
  float*    rope = (float*)W;
  ushort_t* vth = (ushort_t*)(W + 262144);
  ushort_t* vtl = (ushort_t*)(W + 262144 + HB);
  char* C0 = W + 262144 + 2 * HB;
  ushort_t* qhi = (ushort_t*)(C0);
  ushort_t* qlo = (ushort_t*)(C0 + HB);
  ushort_t* khi = (ushort_t*)(C0 + 2 * HB);
  ushort_t* klo = (ushort_t*)(C0 + 3 * HB);
  ushort_t* woth = (ushort_t*)(C0);
  ushort_t* wotl = woth + 589824;
  char* D0 = C0 + 4 * HB;
  ushort_t* abh = (ushort_t*)(D0);
  ushort_t* abl = (ushort_t*)(D0 + HB);
  ushort_t* wqth = (ushort_t*)d_out;            ushort_t* wqtl = wqth + 589824;
  ushort_t* wkth = wqth + 1179648;              ushort_t* wktl = wkth + 589824;
  ushort_t* wvth = wqth + 2359296;              ushort_t* wvtl = wvth + 589824;

  prep_kernel<<<496, 256, 0, stream>>>(rope, Wq, wqth, wqtl, Wk, wkth, wktl, Wv, wvth, wvtl);

  const float q_scale = 0.125f * 1.44269504088896340736f;   // (1/8)*log2(e)

  qkv_gemm_kernel<<<dim3(DMODEL / 128, MTOT / 128, 3), 256, 0, stream>>>(
      Xq, Xkv, wqth, wqtl, wkth, wktl, wvth, wvtl, bq, bk, bv,
      qhi, qlo, khi, klo, vth, vtl, rope, q_scale);

  attn_mfma_kernel<<<768, 512, 0, stream>>>(qhi, qlo, khi, klo, vth, vtl, abh, abl);

  wsplit_t_kernel<<<dim3(12, 12), 256, 0, stream>>>(Wo, woth, wotl);
  out_gemm_kernel<<<dim3(DMODEL / 128, MTOT / 128), 256, 0, stream>>>(
      abh, abl, woth, wotl, bo, out);
}

// Round 17
// 474.279 us; speedup vs baseline: 1.1247x; 1.0252x over previous
//
#include <hip/hip_runtime.h>
#include <cmath>

#define DMODEL 768
#define SEQ    1024
#define NH     12
#define HDIM   64
#define MTOT   16384   // 16 * 1024

typedef unsigned short ushort_t;
typedef __attribute__((ext_vector_type(8))) short short8v;
typedef __attribute__((ext_vector_type(4))) float f32x4;
typedef __attribute__((ext_vector_type(16))) float f32x16;
typedef __attribute__((ext_vector_type(2))) int i32x2v;

union v8u { short8v v; unsigned u[4]; };

__device__ __forceinline__ ushort_t bf16rn(float x) {
  unsigned u = __float_as_uint(x);
  return (ushort_t)((u + 0x7FFFu + ((u >> 16) & 1u)) >> 16);
}
__device__ __forceinline__ void bsplit(float x, ushort_t& h, ushort_t& l) {
  h = bf16rn(x);
  float hf = __uint_as_float((unsigned)h << 16);
  l = bf16rn(x - hf);
}

__device__ __forceinline__ unsigned cvt_pk_bf16(float a, float b) {
  unsigned r;
  asm("v_cvt_pk_bf16_f32 %0, %1, %2" : "=v"(r) : "v"(a), "v"(b));
  return r;
}
__device__ __forceinline__ void bsplit2(float x0, float x1, unsigned& hw, unsigned& lw) {
  hw = cvt_pk_bf16(x0, x1);
  const float h0 = __uint_as_float(hw << 16);
  const float h1 = __uint_as_float(hw & 0xFFFF0000u);
  lw = cvt_pk_bf16(x0 - h0, x1 - h1);
}

__device__ __forceinline__ float vmax3(float a, float b, float c) {
  float d;
  asm("v_max3_f32 %0, %1, %2, %3" : "=v"(d) : "v"(a), "v"(b), "v"(c));
  return d;
}

__device__ __forceinline__ i32x2v pl32(unsigned a, unsigned b) {
  return __builtin_amdgcn_permlane32_swap((int)a, (int)b, false, false);
}

__device__ __forceinline__ void gld16(const void* g, void* l) {
  __builtin_amdgcn_global_load_lds(
      (const __attribute__((address_space(1))) int*)g,
      (__attribute__((address_space(3))) int*)l, 16, 0, 0);
}

// ---------------------------------------------------------------------------
// Weight transpose+split body: W [768k][768n] fp32 -> hi/lo bf16 [768n][768k]
// ---------------------------------------------------------------------------
__device__ __forceinline__
void wsplit_body(const float* __restrict__ W, ushort_t* __restrict__ TH,
                 ushort_t* __restrict__ TL, int kt, int nt, int t, float* Tls) {
  float (*T)[65] = (float(*)[65])Tls;
  const int r = t >> 2, c4 = (t & 3) * 16;
  const float* src = W + (size_t)(kt * 64 + r) * DMODEL + nt * 64 + c4;
#pragma unroll
  for (int i = 0; i < 16; i += 4)
    *(float4*)&T[r][c4 + i] = *(const float4*)&src[i];
  __syncthreads();
  short8v h0, h1, l0, l1;
#pragma unroll
  for (int i = 0; i < 8; ++i) {
    ushort_t hh, ll;
    bsplit(T[c4 + i][r], hh, ll);
    h0[i] = (short)hh; l0[i] = (short)ll;
  }
#pragma unroll
  for (int i = 0; i < 8; ++i) {
    ushort_t hh, ll;
    bsplit(T[c4 + 8 + i][r], hh, ll);
    h1[i] = (short)hh; l1[i] = (short)ll;
  }
  const size_t o = (size_t)(nt * 64 + r) * DMODEL + kt * 64 + c4;
  *(short8v*)&TH[o] = h0; *(short8v*)&TH[o + 8] = h1;
  *(short8v*)&TL[o] = l0; *(short8v*)&TL[o + 8] = l1;
}

// ---------------------------------------------------------------------------
// Prep kernel: blocks 0..63 = RoPE tables; 64.. = Wq/Wk/Wv transpose+split
// ---------------------------------------------------------------------------
__global__ __launch_bounds__(256)
void prep_kernel(float* __restrict__ tab,
                 const float* __restrict__ Wq, ushort_t* __restrict__ QH, ushort_t* __restrict__ QL,
                 const float* __restrict__ Wk, ushort_t* __restrict__ KH, ushort_t* __restrict__ KL,
                 const float* __restrict__ Wv, ushort_t* __restrict__ VH, ushort_t* __restrict__ VL) {
  __shared__ __align__(16) float Tls[64 * 65];
  const int bx = blockIdx.x, t = threadIdx.x;
  if (bx < 64) {
    int idx = bx * 256 + t;
    int l = idx >> 4, p = idx & 15;
    double u = ((double)(l & 31) + 0.5) / 32.0;
    double v = ((double)(l >> 5) + 0.5) / 32.0;
    double freq = (double)p / (15.0 + 1e-9);
    double inv = pow(10000.0, -freq);
    tab[idx]         = (float)cos(u * inv);
    tab[16384 + idx] = (float)sin(u * inv);
    tab[32768 + idx] = (float)cos(v * inv);
    tab[49152 + idx] = (float)sin(v * inv);
    return;
  }
  const int wi = (bx - 64) / 144, b = (bx - 64) % 144;
  const int kt = b % 12, nt = b / 12;
  if (wi == 0)      wsplit_body(Wq, QH, QL, kt, nt, t, Tls);
  else if (wi == 1) wsplit_body(Wk, KH, KL, kt, nt, t, Tls);
  else              wsplit_body(Wv, VH, VL, kt, nt, t, Tls);
}

// standalone wsplit for Wo (must run after attn: output aliases q-buffers)
__global__ __launch_bounds__(256)
void wsplit_t_kernel(const float* __restrict__ W, ushort_t* __restrict__ TH,
                     ushort_t* __restrict__ TL) {
  __shared__ __align__(16) float Tls[64 * 65];
  wsplit_body(W, TH, TL, blockIdx.x, blockIdx.y, threadIdx.x, Tls);
}

// ---------------------------------------------------------------------------
// Fused QKV GEMM, XCD-aware panel swizzle. 1-D grid, 2304 blocks.
// id -> xcd=id&7, s=id>>3, panel q=xcd*48+s/6 (0..383), xt=s%6.
// Panel q -> z=q%3 (Q/K/V), yt=q/3: the 6 n-tiles of one (yt,z) panel run
// CONCURRENTLY on one XCD (A-panel fetched once into that L2); z=1,2 panels
// with the same Xkv rows are temporally adjacent (Xkv fetched once).
// ---------------------------------------------------------------------------
__global__ __launch_bounds__(256)
void qkv_gemm_kernel(const float* __restrict__ Xq, const float* __restrict__ Xkv,
                     const ushort_t* __restrict__ QWh, const ushort_t* __restrict__ QWl,
                     const ushort_t* __restrict__ KWh, const ushort_t* __restrict__ KWl,
                     const ushort_t* __restrict__ VWh, const ushort_t* __restrict__ VWl,
                     const float* __restrict__ bq, const float* __restrict__ bk,
                     const float* __restrict__ bv,
                     ushort_t* __restrict__ qhi, ushort_t* __restrict__ qlo,
                     ushort_t* __restrict__ khi, ushort_t* __restrict__ klo,
                     ushort_t* __restrict__ vth, ushort_t* __restrict__ vtl,
                     const float* __restrict__ rope, float q_scale) {
  __shared__ __align__(16) unsigned char Araw[16384];   // fp32 A tile
  __shared__ __align__(16) ushort_t Bh[128][32];
  __shared__ __align__(16) ushort_t Bl[128][32];
  float* Afs = (float*)Araw;

  const int id = blockIdx.x;
  const int xcd = id & 7, s = id >> 3;
  const int q = xcd * 48 + s / 6;            // panel 0..383
  const int xt = s % 6;                      // n-tile
  const int z = q % 3, yt = q / 3;           // source / m-tile

  const float* Af = (z == 0) ? Xq : Xkv;
  const ushort_t* Bhi = (z == 0) ? QWh : (z == 1) ? KWh : VWh;
  const ushort_t* Blo = (z == 0) ? QWl : (z == 1) ? KWl : VWl;
  const float* bias = (z == 0) ? bq : (z == 1) ? bk : bv;
  ushort_t* Ohi = (z == 0) ? qhi : (z == 1) ? khi : vth;
  ushort_t* Olo = (z == 0) ? qlo : (z == 1) ? klo : vtl;
  const float oscale = (z == 0) ? q_scale : 1.0f;

  const int t = threadIdx.x, lane = t & 63, w = t >> 6;
  const int l15 = lane & 15, l4 = lane >> 4;
  const int wm = w >> 1, wn = w & 1;
  const int m0 = yt * 128, n0 = xt * 128;

  const int crow = t >> 2, ccc = (t & 3) * 8;
  const ushort_t* pBh0 = Bhi + (size_t)(n0 + crow) * DMODEL + ccc;
  const ushort_t* pBh1 = pBh0 + (size_t)64 * DMODEL;
  const ushort_t* pBl0 = Blo + (size_t)(n0 + crow) * DMODEL + ccc;
  const ushort_t* pBl1 = pBl0 + (size_t)64 * DMODEL;
  void* dBh0 = &Bh[crow][ccc];      void* dBh1 = &Bh[crow + 64][ccc];
  void* dBl0 = &Bl[crow][ccc];      void* dBl1 = &Bl[crow + 64][ccc];

  const int sr8 = lane >> 3, sc8 = lane & 7, sg = sc8 ^ sr8;

  f32x4 acc[4][4] = {};

  for (int ks = 0; ks < DMODEL / 32; ++ks) {
    __syncthreads();
#pragma unroll
    for (int j = 0; j < 4; ++j) {
      const int row = j * 32 + w * 8 + sr8;
      gld16(Af + (size_t)(m0 + row) * DMODEL + ks * 32 + sg * 4,
            &Afs[row * 32 + sc8 * 4]);
    }
    gld16(pBh0, dBh0); gld16(pBh1, dBh1);
    gld16(pBl0, dBl0); gld16(pBl1, dBl1);
    pBh0 += 32; pBh1 += 32; pBl0 += 32; pBl1 += 32;
    __syncthreads();

    short8v afh[4], afl[4], bfh[4], bfl[4];
#pragma unroll
    for (int f = 0; f < 4; ++f) {
      const int row = wm * 64 + f * 16 + l15;
      const int rs = l15 & 7;
      const float* ap = Afs + row * 32;
      const f32x4 x0 = *(const f32x4*)(ap + (((2 * l4)     ^ rs) * 4));
      const f32x4 x1 = *(const f32x4*)(ap + (((2 * l4 + 1) ^ rs) * 4));
      v8u hh, ll;
      bsplit2(x0[0], x0[1], hh.u[0], ll.u[0]);
      bsplit2(x0[2], x0[3], hh.u[1], ll.u[1]);
      bsplit2(x1[0], x1[1], hh.u[2], ll.u[2]);
      bsplit2(x1[2], x1[3], hh.u[3], ll.u[3]);
      afh[f] = hh.v; afl[f] = ll.v;
      bfh[f] = *(const short8v*)&Bh[wn * 64 + f * 16 + l15][l4 * 8];
      bfl[f] = *(const short8v*)&Bl[wn * 64 + f * 16 + l15][l4 * 8];
    }
#pragma unroll
    for (int mf = 0; mf < 4; ++mf)
#pragma unroll
      for (int nf = 0; nf < 4; ++nf) {
        acc[mf][nf] = __builtin_amdgcn_mfma_f32_16x16x32_bf16(afh[mf], bfh[nf], acc[mf][nf], 0, 0, 0);
        acc[mf][nf] = __builtin_amdgcn_mfma_f32_16x16x32_bf16(afl[mf], bfh[nf], acc[mf][nf], 0, 0, 0);
        acc[mf][nf] = __builtin_amdgcn_mfma_f32_16x16x32_bf16(afh[mf], bfl[nf], acc[mf][nf], 0, 0, 0);
      }
  }

  float bcol[4];
#pragma unroll
  for (int nf = 0; nf < 4; ++nf) bcol[nf] = bias[n0 + wn * 64 + nf * 16 + l15];

  if (z == 2) {
    // fused V^T epilogue
    ushort_t* hiT = (ushort_t*)Araw;
    ushort_t* loTa = (ushort_t*)Bh;
    ushort_t* loTb = (ushort_t*)Bl;
    const int nb = yt >> 3;
    const int l0 = (yt & 7) * 128;
#pragma unroll
    for (int hs = 0; hs < 2; ++hs) {
      __syncthreads();
      if (wn == hs) {
#pragma unroll
        for (int mf = 0; mf < 4; ++mf)
#pragma unroll
          for (int r = 0; r < 4; ++r) {
            const int ll = wm * 64 + mf * 16 + l4 * 4 + r;
            const int lg = ll >> 3, li = ll & 7;
            unsigned h01, lo01, h23, lo23;
            bsplit2(acc[mf][0][r] + bcol[0], acc[mf][1][r] + bcol[1], h01, lo01);
            bsplit2(acc[mf][2][r] + bcol[2], acc[mf][3][r] + bcol[3], h23, lo23);
            const ushort_t hv[4] = {(ushort_t)(h01 & 0xFFFFu), (ushort_t)(h01 >> 16),
                                    (ushort_t)(h23 & 0xFFFFu), (ushort_t)(h23 >> 16)};
            const ushort_t lv[4] = {(ushort_t)(lo01 & 0xFFFFu), (ushort_t)(lo01 >> 16),
                                    (ushort_t)(lo23 & 0xFFFFu), (ushort_t)(lo23 >> 16)};
#pragma unroll
            for (int nf = 0; nf < 4; ++nf) {
              const int d = nf * 16 + l15;
              const int off = ((lg ^ (d & 7)) << 3) + li;
              hiT[d * 128 + off] = hv[nf];
              if (nf < 2) loTa[d * 128 + off] = lv[nf];
              else        loTb[(d - 32) * 128 + off] = lv[nf];
            }
          }
      }
      __syncthreads();
      {
        const int d = t >> 2;
        const int hglob = xt * 2 + hs;
        const size_t dst = ((size_t)(nb * NH + hglob) * HDIM + d) * SEQ + l0;
#pragma unroll
        for (int j = 0; j < 4; ++j) {
          const int lg = (t & 3) * 4 + j;
          const int off = (lg ^ (d & 7)) << 3;
          const short8v hv = *(const short8v*)&hiT[d * 128 + off];
          const short8v lv = (d < 32) ? *(const short8v*)&loTa[d * 128 + off]
                                      : *(const short8v*)&loTb[(d - 32) * 128 + off];
          *(short8v*)&Ohi[dst + lg * 8] = hv;
          *(short8v*)&Olo[dst + lg * 8] = lv;
        }
      }
    }
  } else {
    const int h = xt * 2 + wn;
#pragma unroll
    for (int mf = 0; mf < 4; ++mf)
#pragma unroll
      for (int r = 0; r < 4; ++r) {
        const int m = m0 + wm * 64 + mf * 16 + l4 * 4 + r;
        const int l = m & (SEQ - 1);
        const int nb = m >> 10;
        const size_t orow = ((size_t)(nb * NH + h) * SEQ + l) * HDIM;
        float vv[4];
#pragma unroll
        for (int nf = 0; nf < 4; ++nf) {
          float v = acc[mf][nf][r] + bcol[nf];
          const float vp = __shfl_xor(v, 1, 64);
          const int tb = (nf < 2) ? 0 : 32768;
          const int pi = (nf & 1) * 8 + (l15 >> 1);
          const float c = rope[tb + l * 16 + pi];
          const float s2 = rope[tb + 16384 + l * 16 + pi];
          v = (l15 & 1) ? (vp * s2 + v * c) : (v * c - vp * s2);
          v *= oscale;   // Q: log2e/8 (exp2-domain); K: 1.0
          vv[nf] = v;
        }
        unsigned h01, l01, h23, l23;
        bsplit2(vv[0], vv[1], h01, l01);
        bsplit2(vv[2], vv[3], h23, l23);
        Ohi[orow + 0 * 16 + l15] = (ushort_t)(h01 & 0xFFFFu);
        Ohi[orow + 1 * 16 + l15] = (ushort_t)(h01 >> 16);
        Ohi[orow + 2 * 16 + l15] = (ushort_t)(h23 & 0xFFFFu);
        Ohi[orow + 3 * 16 + l15] = (ushort_t)(h23 >> 16);
        Olo[orow + 0 * 16 + l15] = (ushort_t)(l01 & 0xFFFFu);
        Olo[orow + 1 * 16 + l15] = (ushort_t)(l01 >> 16);
        Olo[orow + 2 * 16 + l15] = (ushort_t)(l23 & 0xFFFFu);
        Olo[orow + 3 * 16 + l15] = (ushort_t)(l23 >> 16);
      }
  }
}

// ---------------------------------------------------------------------------
// Final projection GEMM (pre-split bf16 A, fp32 C), XCD-aware panel swizzle.
// 768 blocks: xcd=id&7, s=id>>3, yt=xcd*16+s/6, xt=s%6.
// ---------------------------------------------------------------------------
__global__ __launch_bounds__(256)
void out_gemm_kernel(const ushort_t* __restrict__ Ahi, const ushort_t* __restrict__ Alo,
                     const ushort_t* __restrict__ Bhi, const ushort_t* __restrict__ Blo,
                     const float* __restrict__ bias, float* __restrict__ Cout) {
  __shared__ __align__(16) ushort_t Ah[128][32];
  __shared__ __align__(16) ushort_t Al[128][32];
  __shared__ __align__(16) ushort_t Bh[128][32];
  __shared__ __align__(16) ushort_t Bl[128][32];

  const int id = blockIdx.x;
  const int xcd = id & 7, s = id >> 3;
  const int yt = xcd * 16 + s / 6, xt = s % 6;

  const int t = threadIdx.x, lane = t & 63, w = t >> 6;
  const int l15 = lane & 15, l4 = lane >> 4;
  const int wm = w >> 1, wn = w & 1;
  const int m0 = yt * 128, n0 = xt * 128;

  const int crow = t >> 2, ccc = (t & 3) * 8;
  const ushort_t* pAh0 = Ahi + (size_t)(m0 + crow) * DMODEL + ccc;
  const ushort_t* pAh1 = pAh0 + (size_t)64 * DMODEL;
  const ushort_t* pAl0 = Alo + (size_t)(m0 + crow) * DMODEL + ccc;
  const ushort_t* pAl1 = pAl0 + (size_t)64 * DMODEL;
  const ushort_t* pBh0 = Bhi + (size_t)(n0 + crow) * DMODEL + ccc;
  const ushort_t* pBh1 = pBh0 + (size_t)64 * DMODEL;
  const ushort_t* pBl0 = Blo + (size_t)(n0 + crow) * DMODEL + ccc;
  const ushort_t* pBl1 = pBl0 + (size_t)64 * DMODEL;
  void* dAh0 = &Ah[crow][ccc];      void* dAh1 = &Ah[crow + 64][ccc];
  void* dAl0 = &Al[crow][ccc];      void* dAl1 = &Al[crow + 64][ccc];
  void* dBh0 = &Bh[crow][ccc];      void* dBh1 = &Bh[crow + 64][ccc];
  void* dBl0 = &Bl[crow][ccc];      void* dBl1 = &Bl[crow + 64][ccc];

  f32x4 acc[4][4] = {};

  for (int ks = 0; ks < DMODEL / 32; ++ks) {
    __syncthreads();
    gld16(pAh0, dAh0); gld16(pAh1, dAh1);
    gld16(pAl0, dAl0); gld16(pAl1, dAl1);
    gld16(pBh0, dBh0); gld16(pBh1, dBh1);
    gld16(pBl0, dBl0); gld16(pBl1, dBl1);
    pAh0 += 32; pAh1 += 32; pAl0 += 32; pAl1 += 32;
    pBh0 += 32; pBh1 += 32; pBl0 += 32; pBl1 += 32;
    __syncthreads();

    short8v afh[4], afl[4], bfh[4], bfl[4];
#pragma unroll
    for (int f = 0; f < 4; ++f) {
      afh[f] = *(const short8v*)&Ah[wm * 64 + f * 16 + l15][l4 * 8];
      afl[f] = *(const short8v*)&Al[wm * 64 + f * 16 + l15][l4 * 8];
      bfh[f] = *(const short8v*)&Bh[wn * 64 + f * 16 + l15][l4 * 8];
      bfl[f] = *(const short8v*)&Bl[wn * 64 + f * 16 + l15][l4 * 8];
    }
#pragma unroll
    for (int mf = 0; mf < 4; ++mf)
#pragma unroll
      for (int nf = 0; nf < 4; ++nf) {
        acc[mf][nf] = __builtin_amdgcn_mfma_f32_16x16x32_bf16(afh[mf], bfh[nf], acc[mf][nf], 0, 0, 0);
        acc[mf][nf] = __builtin_amdgcn_mfma_f32_16x16x32_bf16(afl[mf], bfh[nf], acc[mf][nf], 0, 0, 0);
        acc[mf][nf] = __builtin_amdgcn_mfma_f32_16x16x32_bf16(afh[mf], bfl[nf], acc[mf][nf], 0, 0, 0);
      }
  }

  float bcol[4];
#pragma unroll
  for (int nf = 0; nf < 4; ++nf) bcol[nf] = bias[n0 + wn * 64 + nf * 16 + l15];

#pragma unroll
  for (int mf = 0; mf < 4; ++mf)
#pragma unroll
    for (int r = 0; r < 4; ++r) {
      const int m = m0 + wm * 64 + mf * 16 + l4 * 4 + r;
#pragma unroll
      for (int nf = 0; nf < 4; ++nf)
        Cout[(size_t)m * DMODEL + n0 + wn * 64 + nf * 16 + l15] = acc[mf][nf][r] + bcol[nf];
    }
}

// ---------------------------------------------------------------------------
// Flash attention (R15 config, unchanged): QBLK=256 / 8 waves, 32x32x16 MFMA,
// swapped QK^T, permlane32_swap P-redistribution, K+V double-buffered via
// global_load_lds + pre-swizzled source, 1 barrier/kt, 64 KB LDS.
// ---------------------------------------------------------------------------
__global__ __launch_bounds__(512)
void attn_mfma_kernel(const ushort_t* __restrict__ qh, const ushort_t* __restrict__ ql,
                      const ushort_t* __restrict__ kh, const ushort_t* __restrict__ kl,
                      const ushort_t* __restrict__ vth, const ushort_t* __restrict__ vtl,
                      ushort_t* __restrict__ abh, ushort_t* __restrict__ abl) {
  __shared__ __align__(16) ushort_t KHs[2][64][64];
  __shared__ __align__(16) ushort_t KLs[2][64][64];
  __shared__ __align__(16) ushort_t VHs[2][64][64];
  __shared__ __align__(16) ushort_t VLs[2][64][64];

  const int t = threadIdx.x;
  const int lane = t & 63, w = t >> 6;       // 8 waves
  const int l31 = lane & 31, l1 = lane >> 5;

  const int bid = blockIdx.x;                // 768 blocks
  const int xcd = bid & 7, rest = bid >> 3;
  const int qt = rest & 3;                   // 4 q-tiles of 256 rows
  const int hl = (rest >> 2) * 8 + xcd;      // head pinned to XCD
  const int h = hl % NH, n = hl / NH;

  const size_t base = (size_t)(n * NH + h) * (SEQ * HDIM);

  short8v qfh[4], qfl[4];
  {
    const size_t qoff = base + (size_t)(qt * 256 + w * 32 + l31) * HDIM + l1 * 8;
#pragma unroll
    for (int ks = 0; ks < 4; ++ks) {
      qfh[ks] = *(const short8v*)&qh[qoff + ks * 16];
      qfl[ks] = *(const short8v*)&ql[qoff + ks * 16];
    }
  }

  const int srow = lane >> 3;
  const int schk = (lane & 7) ^ srow;
  const size_t kof = base + (size_t)(w * 8 + srow) * HDIM + schk * 8;
  const size_t vof = base + (size_t)(w * 8 + srow) * SEQ + schk * 8;
  const int dr = w * 8 + srow, dc = (lane & 7) * 8;

  f32x16 Oa0 = {}, Oa1 = {};
  f32x16 lpv = {};
  float mrun = 0.0f;

#define ATTN_ISSUE(kt_, b_) do {                                            \
    const size_t ko_ = (size_t)(kt_) * (64 * HDIM);                         \
    const size_t vo_ = (size_t)(kt_) * 64;                                  \
    gld16(kh  + kof + ko_, &KHs[b_][dr][dc]);                               \
    gld16(kl  + kof + ko_, &KLs[b_][dr][dc]);                               \
    gld16(vth + vof + vo_, &VHs[b_][dr][dc]);                               \
    gld16(vtl + vof + vo_, &VLs[b_][dr][dc]);                               \
  } while (0)

  ATTN_ISSUE(0, 0);

  for (int kt = 0; kt < 16; ++kt) {
    const int cur = kt & 1;
    __syncthreads();
    if (kt < 15) ATTN_ISSUE(kt + 1, cur ^ 1);

    f32x16 S0 = {}, S1 = {};
    __builtin_amdgcn_s_setprio(1);
#pragma unroll
    for (int ks = 0; ks < 4; ++ks) {
      const int cc = ((2 * ks + l1) ^ (l31 & 7)) * 8;
      const short8v k0h = *(const short8v*)&KHs[cur][l31][cc];
      const short8v k0l = *(const short8v*)&KLs[cur][l31][cc];
      const short8v k1h = *(const short8v*)&KHs[cur][32 + l31][cc];
      const short8v k1l = *(const short8v*)&KLs[cur][32 + l31][cc];
      S0 = __builtin_amdgcn_mfma_f32_32x32x16_bf16(k0h, qfh[ks], S0, 0, 0, 0);
      S1 = __builtin_amdgcn_mfma_f32_32x32x16_bf16(k1h, qfh[ks], S1, 0, 0, 0);
      S0 = __builtin_amdgcn_mfma_f32_32x32x16_bf16(k0l, qfh[ks], S0, 0, 0, 0);
      S1 = __builtin_amdgcn_mfma_f32_32x32x16_bf16(k1l, qfh[ks], S1, 0, 0, 0);
      S0 = __builtin_amdgcn_mfma_f32_32x32x16_bf16(k0h, qfl[ks], S0, 0, 0, 0);
      S1 = __builtin_amdgcn_mfma_f32_32x32x16_bf16(k1h, qfl[ks], S1, 0, 0, 0);
    }
    __builtin_amdgcn_s_setprio(0);

    const float a0 = vmax3(S0[0],  S0[1],  S0[2]);
    const float a1 = vmax3(S0[3],  S0[4],  S0[5]);
    const float a2 = vmax3(S0[6],  S0[7],  S0[8]);
    const float a3 = vmax3(S0[9],  S0[10], S0[11]);
    const float a4 = vmax3(S0[12], S0[13], S0[14]);
    const float b0 = vmax3(S1[0],  S1[1],  S1[2]);
    const float b1 = vmax3(S1[3],  S1[4],  S1[5]);
    const float b2 = vmax3(S1[6],  S1[7],  S1[8]);
    const float b3 = vmax3(S1[9],  S1[10], S1[11]);
    const float b4 = vmax3(S1[12], S1[13], S1[14]);
    const float c0 = vmax3(a0, a1, a2);
    const float c1 = vmax3(a3, a4, S0[15]);
    const float c2 = vmax3(b0, b1, b2);
    const float c3 = vmax3(b3, b4, S1[15]);
    const float mx = fmaxf(vmax3(c0, c1, c2), c3);

    if (__all((mrun == 0.0f) & (mx <= 30.0f))) {
#pragma unroll
      for (int i = 0; i < 16; ++i) {
        S0[i] = __builtin_amdgcn_exp2f(S0[i]);
        S1[i] = __builtin_amdgcn_exp2f(S1[i]);
      }
      lpv += S0 + S1;
    } else {
      const float om = fmaxf(mx, __shfl_xor(mx, 32));
      const float nm = fmaxf(mrun, om);
      const float scl = __builtin_amdgcn_exp2f(mrun - nm);
      mrun = nm;
#pragma unroll
      for (int i = 0; i < 16; ++i) {
        S0[i] = __builtin_amdgcn_exp2f(S0[i] - nm);
        S1[i] = __builtin_amdgcn_exp2f(S1[i] - nm);
      }
      lpv = lpv * scl + (S0 + S1);
      Oa0 = Oa0 * scl;
      Oa1 = Oa1 * scl;
    }

#pragma unroll
    for (int half = 0; half < 2; ++half) {
      unsigned hx[4], hy[4], lx[4], ly[4];
#pragma unroll
      for (int m = 0; m < 4; ++m) {
        float p0, p1, p2, p3;
        if (half == 0) { p0 = S0[4*m]; p1 = S0[4*m+1]; p2 = S0[4*m+2]; p3 = S0[4*m+3]; }
        else           { p0 = S1[4*m]; p1 = S1[4*m+1]; p2 = S1[4*m+2]; p3 = S1[4*m+3]; }
        bsplit2(p0, p1, hx[m], lx[m]);
        bsplit2(p2, p3, hy[m], ly[m]);
      }
      __builtin_amdgcn_s_setprio(1);
#pragma unroll
      for (int kss = 0; kss < 2; ++kss) {
        const i32x2v rhx = pl32(hx[2*kss], hx[2*kss+1]);
        const i32x2v rhy = pl32(hy[2*kss], hy[2*kss+1]);
        const i32x2v rlx = pl32(lx[2*kss], lx[2*kss+1]);
        const i32x2v rly = pl32(ly[2*kss], ly[2*kss+1]);
        v8u bfh, bfl;
        bfh.u[0] = (unsigned)rhx[0]; bfh.u[1] = (unsigned)rhy[0];
        bfh.u[2] = (unsigned)rhx[1]; bfh.u[3] = (unsigned)rhy[1];
        bfl.u[0] = (unsigned)rlx[0]; bfl.u[1] = (unsigned)rly[0];
        bfl.u[2] = (unsigned)rlx[1]; bfl.u[3] = (unsigned)rly[1];
        const int cc = ((4*half + 2*kss + l1) ^ (l31 & 7)) * 8;
        const short8v v0h = *(const short8v*)&VHs[cur][l31][cc];
        const short8v v0l = *(const short8v*)&VLs[cur][l31][cc];
        const short8v v1h = *(const short8v*)&VHs[cur][32 + l31][cc];
        const short8v v1l = *(const short8v*)&VLs[cur][32 + l31][cc];
        Oa0 = __builtin_amdgcn_mfma_f32_32x32x16_bf16(v0h, bfh.v, Oa0, 0, 0, 0);
        Oa1 = __builtin_amdgcn_mfma_f32_32x32x16_bf16(v1h, bfh.v, Oa1, 0, 0, 0);
        Oa0 = __builtin_amdgcn_mfma_f32_32x32x16_bf16(v0l, bfh.v, Oa0, 0, 0, 0);
        Oa1 = __builtin_amdgcn_mfma_f32_32x32x16_bf16(v1l, bfh.v, Oa1, 0, 0, 0);
        Oa0 = __builtin_amdgcn_mfma_f32_32x32x16_bf16(v0h, bfl.v, Oa0, 0, 0, 0);
        Oa1 = __builtin_amdgcn_mfma_f32_32x32x16_bf16(v1h, bfl.v, Oa1, 0, 0, 0);
      }
      __builtin_amdgcn_s_setprio(0);
    }
  }

  float lp = ((((lpv[0]+lpv[1])+(lpv[2]+lpv[3]))+((lpv[4]+lpv[5])+(lpv[6]+lpv[7])))
           + (((lpv[8]+lpv[9])+(lpv[10]+lpv[11]))+((lpv[12]+lpv[13])+(lpv[14]+lpv[15]))));
  lp += __shfl_xor(lp, 32);
  const float inv = 1.0f / lp;
  const size_t orow = ((size_t)n * SEQ + qt * 256 + w * 32 + l31) * DMODEL + h * HDIM;
#pragma unroll
  for (int jd = 0; jd < 2; ++jd) {
#pragma unroll
    for (int g = 0; g < 4; ++g) {
      float o0, o1, o2, o3;
      if (jd == 0) { o0 = Oa0[4*g]; o1 = Oa0[4*g+1]; o2 = Oa0[4*g+2]; o3 = Oa0[4*g+3]; }
      else         { o0 = Oa1[4*g]; o1 = Oa1[4*g+1]; o2 = Oa1[4*g+2]; o3 = Oa1[4*g+3]; }
      o0 *= inv; o1 *= inv; o2 *= inv; o3 *= inv;
      unsigned h01, l01, h23, l23;
      bsplit2(o0, o1, h01, l01);
      bsplit2(o2, o3, h23, l23);
      const int d = 32 * jd + 8 * g + 4 * l1;
      uint2 sh; sh.x = h01; sh.y = h23;
      uint2 sl; sl.x = l01; sl.y = l23;
      *(uint2*)&abh[orow + d] = sh;
      *(uint2*)&abl[orow + d] = sl;
    }
  }
#undef ATTN_ISSUE
}

// ---------------------------------------------------------------------------
extern "C" void kernel_launch(void* const* d_in, const int* in_sizes, int n_in,
                              void* d_out, int out_size, void* d_ws, size_t ws_size,
                              hipStream_t stream) {
  (void)in_sizes; (void)n_in; (void)out_size;
  const float* Xq  = (const float*)d_in[0];
  const float* Xkv = (const float*)d_in[1];
  const float* Wq  = (const float*)d_in[2];
  const float* bq  = (const float*)d_in[3];
  const float* Wk  = (const float*)d_in[4];
  const float* bk  = (const float*)d_in[5];
  const float* Wv  = (const float*)d_in[6];
  const float* bv  = (const float*)d_in[7];
  const float* Wo  = (const float*)d_in[8];
  const float* bo  = (const float*)d_in[9];
  float* out = (float*)d_out;

  if (ws_size < 201588736ull) return;
  char* W = (char*)d_ws;
  const size_t HB = 25165824ull;
  float*    rope = (float*)W;
  ushort_t* vth = (ushort_t*)(W + 262144);
  ushort_t* vtl = (ushort_t*)(W + 262144 + HB);
  char* C0 = W + 262144 + 2 * HB;
  ushort_t* qhi = (ushort_t*)(C0);
  ushort_t* qlo = (ushort_t*)(C0 + HB);
  ushort_t* khi = (ushort_t*)(C0 + 2 * HB);
  ushort_t* klo = (ushort_t*)(C0 + 3 * HB);
  ushort_t* woth = (ushort_t*)(C0);
  ushort_t* wotl = woth + 589824;
  char* D0 = C0 + 4 * HB;
  ushort_t* abh = (ushort_t*)(D0);
  ushort_t* abl = (ushort_t*)(D0 + HB);
  ushort_t* wqth = (ushort_t*)d_out;            ushort_t* wqtl = wqth + 589824;
  ushort_t* wkth = wqth + 1179648;              ushort_t* wktl = wkth + 589824;
  ushort_t* wvth = wqth + 2359296;              ushort_t* wvtl = wvth + 589824;

  prep_kernel<<<496, 256, 0, stream>>>(rope, Wq, wqth, wqtl, Wk, wkth, wktl, Wv, wvth, wvtl);

  const float q_scale = 0.125f * 1.44269504088896340736f;   // (1/8)*log2(e)

  qkv_gemm_kernel<<<2304, 256, 0, stream>>>(
      Xq, Xkv, wqth, wqtl, wkth, wktl, wvth, wvtl, bq, bk, bv,
      qhi, qlo, khi, klo, vth, vtl, rope, q_scale);

  attn_mfma_kernel<<<768, 512, 0, stream>>>(qhi, qlo, khi, klo, vth, vtl, abh, abl);

  wsplit_t_kernel<<<dim3(12, 12), 256, 0, stream>>>(Wo, woth, wotl);
  out_gemm_kernel<<<768, 256, 0, stream>>>(abh, abl, woth, wotl, bo, out);
}